// Round 1
// baseline (556.133 us; speedup 1.0000x reference)
//
#include <hip/hip_runtime.h>
#include <cstdint>
#include <cstddef>

// ---------------------------------------------------------------------------
// SelfAttentionDiff: GN -> QKV (1x1) -> softmax(Q^T K/16) -> V P^T -> proj -> +res
// b=8, c=256, n=64*64=4096, groups=32 (8 ch/group)
// All GEMMs via v_mfma_f32_16x16x32_bf16, fp32 accumulation.
// Fragment conventions (verified-compatible with learn_hip m89/m92 ladder):
//   A-frag: lane l holds A[mbase + (l&15)][kbase + 8*(l>>4) + e], e=0..7 (16B)
//   B-frag: lane l holds B[kbase + 8*(l>>4) + e][nbase + (l&15)]  (stored as [n][k], 16B)
//   D-frag: reg r -> row = 4*(l>>4)+r, col = (l&15)   [HW-verified m89]
// ---------------------------------------------------------------------------

#define NB   8
#define NC   256
#define NPIX 4096
#define NGRP 32
#define CPG  8

typedef __attribute__((ext_vector_type(8))) short bf16x8;
typedef __attribute__((ext_vector_type(4))) short s16x4;
typedef __attribute__((ext_vector_type(8))) short s16x8;
typedef __attribute__((ext_vector_type(4))) float f32x4;

__device__ __forceinline__ short f2bf(float f) {
  union { float f; uint32_t u; } v; v.f = f;
  return (short)((v.u + 0x7fffu + ((v.u >> 16) & 1u)) >> 16);
}

__device__ __forceinline__ f32x4 mfma16(bf16x8 a, bf16x8 b, f32x4 c) {
  return __builtin_amdgcn_mfma_f32_16x16x32_bf16(a, b, c, 0, 0, 0);
}

// ---------------------------------------------------------------------------
// K0: fp32 -> bf16 weight convert (65536 elems per matrix)
__global__ __launch_bounds__(256) void wconv(const float* __restrict__ w,
                                             short* __restrict__ o) {
  int i = (blockIdx.x * 256 + threadIdx.x) * 4;
  float4 v = *reinterpret_cast<const float4*>(w + i);
  s16x4 p;
  p[0] = f2bf(v.x); p[1] = f2bf(v.y); p[2] = f2bf(v.z); p[3] = f2bf(v.w);
  *reinterpret_cast<s16x4*>(o + i) = p;
}

// ---------------------------------------------------------------------------
// K1: GroupNorm. One block per (b,g). Writes x_dash transposed: xdt[b][pix][c] bf16.
__global__ __launch_bounds__(256) void gnorm(const float* __restrict__ x,
                                             const float* __restrict__ gw,
                                             const float* __restrict__ gb,
                                             short* __restrict__ xdt) {
  int b = blockIdx.x >> 5;
  int g = blockIdx.x & 31;
  const float* xp = x + ((size_t)b * NC + (size_t)g * CPG) * NPIX;
  int t = threadIdx.x;

  float s = 0.f, ss = 0.f;
  const float4* xp4 = reinterpret_cast<const float4*>(xp);
  for (int i = t; i < (CPG * NPIX) / 4; i += 256) {
    float4 v = xp4[i];
    s  += v.x + v.y + v.z + v.w;
    ss += v.x * v.x + v.y * v.y + v.z * v.z + v.w * v.w;
  }
  for (int m = 32; m; m >>= 1) { s += __shfl_xor(s, m); ss += __shfl_xor(ss, m); }
  __shared__ float red[10];
  int wid = t >> 6;
  if ((t & 63) == 0) { red[wid] = s; red[4 + wid] = ss; }
  __syncthreads();
  if (t == 0) {
    float a  = red[0] + red[1] + red[2] + red[3];
    float b2 = red[4] + red[5] + red[6] + red[7];
    float mean = a * (1.f / 32768.f);
    float var  = b2 * (1.f / 32768.f) - mean * mean;
    red[8] = mean;
    red[9] = rsqrtf(var + 1e-5f);
  }
  __syncthreads();
  float mean = red[8], rstd = red[9];

  float wv2[CPG], bv2[CPG];
  for (int cc = 0; cc < CPG; ++cc) {
    float wgt = gw[g * CPG + cc] * rstd;
    wv2[cc] = wgt;
    bv2[cc] = gb[g * CPG + cc] - mean * wgt;
  }
  for (int pix = t; pix < NPIX; pix += 256) {
    s16x8 pk;
    for (int cc = 0; cc < CPG; ++cc)
      pk[cc] = f2bf(fmaf(xp[cc * NPIX + pix], wv2[cc], bv2[cc]));
    *reinterpret_cast<s16x8*>(&xdt[((size_t)b * NPIX + pix) * NC + g * CPG]) = pk;
  }
}

// ---------------------------------------------------------------------------
// K2: QKV GEMM. grid(64 ntiles, 8 b, 3 mat). OUT[o][n] = sum_c W[o][c] xd[c][n] + bias.
// Q,K stored transposed [b][n][o]; V stored [b][o][n]. LDS tile XOR-swizzled (T2).
__global__ __launch_bounds__(256) void qkv_gemm(
    const short* __restrict__ wq_bf, const short* __restrict__ wk_bf,
    const short* __restrict__ wv_bf,
    const float* __restrict__ bq, const float* __restrict__ bk,
    const float* __restrict__ bv,
    const short* __restrict__ xdt,
    short* __restrict__ qt, short* __restrict__ kt, short* __restrict__ vv) {
  int nt = blockIdx.x, b = blockIdx.y, mi = blockIdx.z;
  const short* W; const float* bia;
  if (mi == 0)      { W = wq_bf; bia = bq; }
  else if (mi == 1) { W = wk_bf; bia = bk; }
  else              { W = wv_bf; bia = bv; }

  __shared__ short xtile[64 * 256];
  __shared__ float bias_lds[256];
  int t = threadIdx.x;
  const short* xg = xdt + ((size_t)b * NPIX + nt * 64) * NC;
  for (int it = 0; it < 8; ++it) {
    int id = t + it * 256, row = id >> 5, part = id & 31;
    *reinterpret_cast<uint4*>(&xtile[row * 256 + (part ^ (row & 7)) * 8]) =
        *reinterpret_cast<const uint4*>(&xg[(size_t)row * 256 + part * 8]);
  }
  bias_lds[t] = bia[t];
  __syncthreads();

  int w = t >> 6, lane = t & 63, g = lane >> 4, lr = lane & 15;
  f32x4 acc[4][4];
  f32x4 zz = {0.f, 0.f, 0.f, 0.f};
  for (int i = 0; i < 4; ++i) for (int j = 0; j < 4; ++j) acc[i][j] = zz;

  for (int c0 = 0; c0 < 256; c0 += 32) {
    bf16x8 af[4], bfr[4];
    for (int mf = 0; mf < 4; ++mf)
      af[mf] = *reinterpret_cast<const bf16x8*>(
          &W[(size_t)(w * 64 + mf * 16 + lr) * 256 + c0 + g * 8]);
    for (int nf = 0; nf < 4; ++nf) {
      int row = nf * 16 + lr;
      bfr[nf] = *reinterpret_cast<const bf16x8*>(
          &xtile[row * 256 + (((c0 >> 3) + g) ^ (row & 7)) * 8]);
    }
    for (int mf = 0; mf < 4; ++mf)
      for (int nf = 0; nf < 4; ++nf)
        acc[mf][nf] = mfma16(af[mf], bfr[nf], acc[mf][nf]);
  }

  if (mi < 2) {
    short* outp = (mi == 0) ? qt : kt;
    for (int mf = 0; mf < 4; ++mf)
      for (int nf = 0; nf < 4; ++nf) {
        int ob = w * 64 + mf * 16 + g * 4;
        int n  = nt * 64 + nf * 16 + lr;
        s16x4 pk;
        for (int r = 0; r < 4; ++r)
          pk[r] = f2bf(acc[mf][nf][r] + bias_lds[ob + r]);
        *reinterpret_cast<s16x4*>(&outp[((size_t)b * NPIX + n) * NC + ob]) = pk;
      }
  } else {
    for (int mf = 0; mf < 4; ++mf)
      for (int nf = 0; nf < 4; ++nf) {
        int ob = w * 64 + mf * 16 + g * 4;
        int n  = nt * 64 + nf * 16 + lr;
        for (int r = 0; r < 4; ++r)
          vv[((size_t)b * NC + ob + r) * NPIX + n] =
              f2bf(acc[mf][nf][r] + bias_lds[ob + r]);
      }
  }
}

// ---------------------------------------------------------------------------
// K3: flash attention. grid(64 itiles, 8 b). Block: 64 q-rows, 4 waves.
// Wave w: softmax rows i_loc in [16w,16w+16); O-acc c-rows [64w,64w+64) x all 64 i.
__global__ __launch_bounds__(256) void attn(
    const short* __restrict__ qt, const short* __restrict__ kt,
    const short* __restrict__ vv, short* __restrict__ ot) {
  int itile = blockIdx.x, b = blockIdx.y;
  __shared__ short ktile[64 * 256];
  __shared__ float P[64 * 68];
  __shared__ float alpha_lds[64];
  __shared__ float lsum_lds[64];

  int t = threadIdx.x, w = t >> 6, lane = t & 63, g = lane >> 4, lr = lane & 15;
  int i0 = itile * 64;

  bf16x8 qf[8];
  {
    const short* qrow = qt + ((size_t)b * NPIX + i0 + w * 16 + lr) * NC;
    for (int ks = 0; ks < 8; ++ks)
      qf[ks] = *reinterpret_cast<const bf16x8*>(&qrow[ks * 32 + g * 8]);
  }

  f32x4 zz = {0.f, 0.f, 0.f, 0.f};
  f32x4 oacc[4][4];
  for (int i = 0; i < 4; ++i) for (int j = 0; j < 4; ++j) oacc[i][j] = zz;
  float m_[4], l_[4];
  for (int r = 0; r < 4; ++r) { m_[r] = -1e30f; l_[r] = 0.f; }

  const short* ktg = kt + (size_t)b * NPIX * NC;
  const short* vg  = vv + (size_t)b * NC * NPIX;
  const float sc = 0.0625f, L2E = 1.44269504f;

  for (int jt = 0; jt < 64; ++jt) {
    __syncthreads();  // previous PV reads of ktile/P complete
    for (int itx = 0; itx < 8; ++itx) {
      int id = t + itx * 256, row = id >> 5, part = id & 31;
      *reinterpret_cast<uint4*>(&ktile[row * 256 + (part ^ (row & 7)) * 8]) =
          *reinterpret_cast<const uint4*>(
              &ktg[(size_t)(jt * 64 + row) * NC + part * 8]);
    }
    __syncthreads();

    // S = Q^T K  (rows 16w..16w+16, cols 0..63)
    f32x4 s[4];
    for (int nf = 0; nf < 4; ++nf) s[nf] = zz;
    for (int ks = 0; ks < 8; ++ks) {
      bf16x8 kf[4];
      for (int nf = 0; nf < 4; ++nf) {
        int row = nf * 16 + lr;
        kf[nf] = *reinterpret_cast<const bf16x8*>(
            &ktile[row * 256 + (((ks * 4) + g) ^ (row & 7)) * 8]);
      }
      for (int nf = 0; nf < 4; ++nf) s[nf] = mfma16(qf[ks], kf[nf], s[nf]);
    }

    // online softmax (rows i_loc = 16w + 4g + r)
    float alpha[4];
    for (int r = 0; r < 4; ++r) {
      float mx = fmaxf(fmaxf(s[0][r], s[1][r]), fmaxf(s[2][r], s[3][r]));
      for (int msk = 1; msk < 16; msk <<= 1) mx = fmaxf(mx, __shfl_xor(mx, msk));
      mx *= sc;
      float mn = fmaxf(m_[r], mx);
      alpha[r] = exp2f((m_[r] - mn) * L2E);
      float ps = 0.f;
      int prow = w * 16 + g * 4 + r;
      for (int nf = 0; nf < 4; ++nf) {
        float p = exp2f((s[nf][r] * sc - mn) * L2E);
        ps += p;
        P[prow * 68 + nf * 16 + lr] = p;
      }
      for (int msk = 1; msk < 16; msk <<= 1) ps += __shfl_xor(ps, msk);
      l_[r] = l_[r] * alpha[r] + ps;
      m_[r] = mn;
    }
    if (lr == 0)
      for (int r = 0; r < 4; ++r) alpha_lds[w * 16 + g * 4 + r] = alpha[r];
    __syncthreads();

    // rescale O, then O += V * P^T
    float av[4];
    for (int nf = 0; nf < 4; ++nf) av[nf] = alpha_lds[nf * 16 + lr];
    for (int mf = 0; mf < 4; ++mf)
      for (int nf = 0; nf < 4; ++nf) oacc[mf][nf] *= av[nf];

    for (int ks2 = 0; ks2 < 2; ++ks2) {
      bf16x8 va[4], pb[4];
      for (int mf = 0; mf < 4; ++mf)
        va[mf] = *reinterpret_cast<const bf16x8*>(
            &vg[(size_t)(w * 64 + mf * 16 + lr) * NPIX + jt * 64 + ks2 * 32 + g * 8]);
      for (int nf = 0; nf < 4; ++nf) {
        const float* pp = &P[(nf * 16 + lr) * 68 + ks2 * 32 + g * 8];
        f32x4 p0 = *reinterpret_cast<const f32x4*>(pp);
        f32x4 p1 = *reinterpret_cast<const f32x4*>(pp + 4);
        bf16x8 pv;
        for (int e = 0; e < 4; ++e) { pv[e] = f2bf(p0[e]); pv[4 + e] = f2bf(p1[e]); }
        pb[nf] = pv;
      }
      for (int mf = 0; mf < 4; ++mf)
        for (int nf = 0; nf < 4; ++nf)
          oacc[mf][nf] = mfma16(va[mf], pb[nf], oacc[mf][nf]);
    }
  }

  if (lr == 0)
    for (int r = 0; r < 4; ++r) lsum_lds[w * 16 + g * 4 + r] = l_[r];
  __syncthreads();

  // write O^T: ot[b][i][c] bf16
  for (int nf = 0; nf < 4; ++nf) {
    float inv = 1.f / lsum_lds[nf * 16 + lr];
    int i = i0 + nf * 16 + lr;
    for (int mf = 0; mf < 4; ++mf) {
      int cb = w * 64 + mf * 16 + g * 4;
      s16x4 pk;
      for (int r = 0; r < 4; ++r) pk[r] = f2bf(oacc[mf][nf][r] * inv);
      *reinterpret_cast<s16x4*>(&ot[((size_t)b * NPIX + i) * NC + cb]) = pk;
    }
  }
}

// ---------------------------------------------------------------------------
// K4: proj + residual. out[b][o][n] = x + gamma*(sum_c wp[o][c]*O[c][n] + bp[o])
__global__ __launch_bounds__(256) void proj_res(
    const short* __restrict__ wp_bf, const float* __restrict__ bp,
    const short* __restrict__ ot, const float* __restrict__ x,
    const float* __restrict__ gamma, float* __restrict__ out) {
  int nt = blockIdx.x, b = blockIdx.y;
  __shared__ short otile[64 * 256];
  __shared__ float bias_lds[256];
  int t = threadIdx.x;
  const short* og = ot + ((size_t)b * NPIX + nt * 64) * NC;
  for (int itx = 0; itx < 8; ++itx) {
    int id = t + itx * 256, row = id >> 5, part = id & 31;
    *reinterpret_cast<uint4*>(&otile[row * 256 + (part ^ (row & 7)) * 8]) =
        *reinterpret_cast<const uint4*>(&og[(size_t)row * 256 + part * 8]);
  }
  bias_lds[t] = bp[t];
  __syncthreads();

  int w = t >> 6, lane = t & 63, g = lane >> 4, lr = lane & 15;
  f32x4 acc[4][4];
  f32x4 zz = {0.f, 0.f, 0.f, 0.f};
  for (int i = 0; i < 4; ++i) for (int j = 0; j < 4; ++j) acc[i][j] = zz;

  for (int c0 = 0; c0 < 256; c0 += 32) {
    bf16x8 af[4], bfr[4];
    for (int mf = 0; mf < 4; ++mf)
      af[mf] = *reinterpret_cast<const bf16x8*>(
          &wp_bf[(size_t)(w * 64 + mf * 16 + lr) * 256 + c0 + g * 8]);
    for (int nf = 0; nf < 4; ++nf) {
      int row = nf * 16 + lr;
      bfr[nf] = *reinterpret_cast<const bf16x8*>(
          &otile[row * 256 + (((c0 >> 3) + g) ^ (row & 7)) * 8]);
    }
    for (int mf = 0; mf < 4; ++mf)
      for (int nf = 0; nf < 4; ++nf)
        acc[mf][nf] = mfma16(af[mf], bfr[nf], acc[mf][nf]);
  }

  float gm = gamma[0];
  for (int mf = 0; mf < 4; ++mf)
    for (int nf = 0; nf < 4; ++nf) {
      int ob = w * 64 + mf * 16 + g * 4;
      int n  = nt * 64 + nf * 16 + lr;
      for (int r = 0; r < 4; ++r) {
        size_t idx = ((size_t)b * NC + ob + r) * NPIX + n;
        out[idx] = x[idx] + gm * (acc[mf][nf][r] + bias_lds[ob + r]);
      }
    }
}

// ---------------------------------------------------------------------------
extern "C" void kernel_launch(void* const* d_in, const int* in_sizes, int n_in,
                              void* d_out, int out_size, void* d_ws, size_t ws_size,
                              hipStream_t stream) {
  (void)in_sizes; (void)n_in; (void)out_size; (void)ws_size;
  const float* x     = (const float*)d_in[0];
  const float* gn_w  = (const float*)d_in[1];
  const float* gn_b  = (const float*)d_in[2];
  const float* wq    = (const float*)d_in[3];
  const float* bq    = (const float*)d_in[4];
  const float* wk    = (const float*)d_in[5];
  const float* bk    = (const float*)d_in[6];
  const float* wv    = (const float*)d_in[7];
  const float* bv    = (const float*)d_in[8];
  const float* wp    = (const float*)d_in[9];
  const float* bp    = (const float*)d_in[10];
  const float* gamma = (const float*)d_in[11];
  float* out = (float*)d_out;

  char* ws = (char*)d_ws;
  const size_t WSZ = 131072;            // 256*256*2B
  const size_t TSZ = (size_t)NB * NPIX * NC * 2;  // 16.78MB
  short* wq_bf = (short*)(ws);
  short* wk_bf = (short*)(ws + WSZ);
  short* wv_bf = (short*)(ws + 2 * WSZ);
  short* wp_bf = (short*)(ws + 3 * WSZ);
  short* xdt   = (short*)(ws + 4 * WSZ);            // reused as Ot after K2
  short* qt    = (short*)(ws + 4 * WSZ + TSZ);
  short* kt    = (short*)(ws + 4 * WSZ + 2 * TSZ);
  short* vv    = (short*)(ws + 4 * WSZ + 3 * TSZ);
  short* ot    = xdt;

  wconv<<<64, 256, 0, stream>>>(wq, wq_bf);
  wconv<<<64, 256, 0, stream>>>(wk, wk_bf);
  wconv<<<64, 256, 0, stream>>>(wv, wv_bf);
  wconv<<<64, 256, 0, stream>>>(wp, wp_bf);

  gnorm<<<256, 256, 0, stream>>>(x, gn_w, gn_b, xdt);

  qkv_gemm<<<dim3(64, 8, 3), 256, 0, stream>>>(wq_bf, wk_bf, wv_bf, bq, bk, bv,
                                               xdt, qt, kt, vv);

  attn<<<dim3(64, 8), 256, 0, stream>>>(qt, kt, vv, ot);

  proj_res<<<dim3(64, 8), 256, 0, stream>>>(wp_bf, bp, ot, x, gamma, out);
}

// Round 2
// 538.825 us; speedup vs baseline: 1.0321x; 1.0321x over previous
//
#include <hip/hip_runtime.h>
#include <cstdint>
#include <cstddef>

// ---------------------------------------------------------------------------
// SelfAttentionDiff: GN -> QKV (1x1) -> softmax(Q^T K/16) -> V P^T -> proj -> +res
// b=8, c=256, n=64*64=4096, groups=32 (8 ch/group)
// All GEMMs via v_mfma_f32_16x16x32_bf16, fp32 accumulation.
// Fragment conventions (verified-compatible with learn_hip m89/m92 ladder):
//   A-frag: lane l holds A[mbase + (l&15)][kbase + 8*(l>>4) + e], e=0..7 (16B)
//   B-frag: lane l holds B[kbase + 8*(l>>4) + e][nbase + (l&15)]  (stored as [n][k], 16B)
//   D-frag: reg r -> row = 4*(l>>4)+r, col = (l&15)   [HW-verified m89]
// ---------------------------------------------------------------------------

#define NB   8
#define NC   256
#define NPIX 4096
#define NGRP 32
#define CPG  8

typedef __attribute__((ext_vector_type(8))) short bf16x8;
typedef __attribute__((ext_vector_type(4))) short s16x4;
typedef __attribute__((ext_vector_type(8))) short s16x8;
typedef __attribute__((ext_vector_type(4))) float f32x4;

__device__ __forceinline__ short f2bf(float f) {
  union { float f; uint32_t u; } v; v.f = f;
  return (short)((v.u + 0x7fffu + ((v.u >> 16) & 1u)) >> 16);
}

__device__ __forceinline__ f32x4 mfma16(bf16x8 a, bf16x8 b, f32x4 c) {
  return __builtin_amdgcn_mfma_f32_16x16x32_bf16(a, b, c, 0, 0, 0);
}

// async 16B global -> LDS (linear dest, per-lane global src)
__device__ __forceinline__ void gload_lds16(const short* g, short* l) {
  __builtin_amdgcn_global_load_lds(
      (const __attribute__((address_space(1))) void*)g,
      (__attribute__((address_space(3))) void*)l, 16, 0, 0);
}

// ---------------------------------------------------------------------------
// K0: fp32 -> bf16 weight convert (65536 elems per matrix)
__global__ __launch_bounds__(256) void wconv(const float* __restrict__ w,
                                             short* __restrict__ o) {
  int i = (blockIdx.x * 256 + threadIdx.x) * 4;
  float4 v = *reinterpret_cast<const float4*>(w + i);
  s16x4 p;
  p[0] = f2bf(v.x); p[1] = f2bf(v.y); p[2] = f2bf(v.z); p[3] = f2bf(v.w);
  *reinterpret_cast<s16x4*>(o + i) = p;
}

// ---------------------------------------------------------------------------
// K1: GroupNorm. One block per (b,g). Writes x_dash transposed: xdt[b][pix][c] bf16.
__global__ __launch_bounds__(256) void gnorm(const float* __restrict__ x,
                                             const float* __restrict__ gw,
                                             const float* __restrict__ gb,
                                             short* __restrict__ xdt) {
  int b = blockIdx.x >> 5;
  int g = blockIdx.x & 31;
  const float* xp = x + ((size_t)b * NC + (size_t)g * CPG) * NPIX;
  int t = threadIdx.x;

  float s = 0.f, ss = 0.f;
  const float4* xp4 = reinterpret_cast<const float4*>(xp);
  for (int i = t; i < (CPG * NPIX) / 4; i += 256) {
    float4 v = xp4[i];
    s  += v.x + v.y + v.z + v.w;
    ss += v.x * v.x + v.y * v.y + v.z * v.z + v.w * v.w;
  }
  for (int m = 32; m; m >>= 1) { s += __shfl_xor(s, m); ss += __shfl_xor(ss, m); }
  __shared__ float red[10];
  int wid = t >> 6;
  if ((t & 63) == 0) { red[wid] = s; red[4 + wid] = ss; }
  __syncthreads();
  if (t == 0) {
    float a  = red[0] + red[1] + red[2] + red[3];
    float b2 = red[4] + red[5] + red[6] + red[7];
    float mean = a * (1.f / 32768.f);
    float var  = b2 * (1.f / 32768.f) - mean * mean;
    red[8] = mean;
    red[9] = rsqrtf(var + 1e-5f);
  }
  __syncthreads();
  float mean = red[8], rstd = red[9];

  float wv2[CPG], bv2[CPG];
  for (int cc = 0; cc < CPG; ++cc) {
    float wgt = gw[g * CPG + cc] * rstd;
    wv2[cc] = wgt;
    bv2[cc] = gb[g * CPG + cc] - mean * wgt;
  }
  for (int pix = t; pix < NPIX; pix += 256) {
    s16x8 pk;
    for (int cc = 0; cc < CPG; ++cc)
      pk[cc] = f2bf(fmaf(xp[cc * NPIX + pix], wv2[cc], bv2[cc]));
    *reinterpret_cast<s16x8*>(&xdt[((size_t)b * NPIX + pix) * NC + g * CPG]) = pk;
  }
}

// ---------------------------------------------------------------------------
// K2: QKV GEMM. grid(64 ntiles, 8 b, 3 mat). OUT[o][n] = sum_c W[o][c] xd[c][n] + bias.
// Q,K stored transposed [b][n][o]; V stored [b][o][n]. LDS tile XOR-swizzled (T2).
__global__ __launch_bounds__(256) void qkv_gemm(
    const short* __restrict__ wq_bf, const short* __restrict__ wk_bf,
    const short* __restrict__ wv_bf,
    const float* __restrict__ bq, const float* __restrict__ bk,
    const float* __restrict__ bv,
    const short* __restrict__ xdt,
    short* __restrict__ qt, short* __restrict__ kt, short* __restrict__ vv) {
  int nt = blockIdx.x, b = blockIdx.y, mi = blockIdx.z;
  const short* W; const float* bia;
  if (mi == 0)      { W = wq_bf; bia = bq; }
  else if (mi == 1) { W = wk_bf; bia = bk; }
  else              { W = wv_bf; bia = bv; }

  __shared__ short xtile[64 * 256];
  __shared__ float bias_lds[256];
  int t = threadIdx.x;
  const short* xg = xdt + ((size_t)b * NPIX + nt * 64) * NC;
  for (int it = 0; it < 8; ++it) {
    int id = t + it * 256, row = id >> 5, part = id & 31;
    *reinterpret_cast<uint4*>(&xtile[row * 256 + (part ^ (row & 7)) * 8]) =
        *reinterpret_cast<const uint4*>(&xg[(size_t)row * 256 + part * 8]);
  }
  bias_lds[t] = bia[t];
  __syncthreads();

  int w = t >> 6, lane = t & 63, g = lane >> 4, lr = lane & 15;
  f32x4 acc[4][4];
  f32x4 zz = {0.f, 0.f, 0.f, 0.f};
  for (int i = 0; i < 4; ++i) for (int j = 0; j < 4; ++j) acc[i][j] = zz;

  for (int c0 = 0; c0 < 256; c0 += 32) {
    bf16x8 af[4], bfr[4];
    for (int mf = 0; mf < 4; ++mf)
      af[mf] = *reinterpret_cast<const bf16x8*>(
          &W[(size_t)(w * 64 + mf * 16 + lr) * 256 + c0 + g * 8]);
    for (int nf = 0; nf < 4; ++nf) {
      int row = nf * 16 + lr;
      bfr[nf] = *reinterpret_cast<const bf16x8*>(
          &xtile[row * 256 + (((c0 >> 3) + g) ^ (row & 7)) * 8]);
    }
    for (int mf = 0; mf < 4; ++mf)
      for (int nf = 0; nf < 4; ++nf)
        acc[mf][nf] = mfma16(af[mf], bfr[nf], acc[mf][nf]);
  }

  if (mi < 2) {
    short* outp = (mi == 0) ? qt : kt;
    for (int mf = 0; mf < 4; ++mf)
      for (int nf = 0; nf < 4; ++nf) {
        int ob = w * 64 + mf * 16 + g * 4;
        int n  = nt * 64 + nf * 16 + lr;
        s16x4 pk;
        for (int r = 0; r < 4; ++r)
          pk[r] = f2bf(acc[mf][nf][r] + bias_lds[ob + r]);
        *reinterpret_cast<s16x4*>(&outp[((size_t)b * NPIX + n) * NC + ob]) = pk;
      }
  } else {
    for (int mf = 0; mf < 4; ++mf)
      for (int nf = 0; nf < 4; ++nf) {
        int ob = w * 64 + mf * 16 + g * 4;
        int n  = nt * 64 + nf * 16 + lr;
        for (int r = 0; r < 4; ++r)
          vv[((size_t)b * NC + ob + r) * NPIX + n] =
              f2bf(acc[mf][nf][r] + bias_lds[ob + r]);
      }
  }
}

// ---------------------------------------------------------------------------
// K3: flash attention. grid(64 itiles, 8 b). Block: 64 q-rows, 4 waves.
// Wave w: softmax rows [16w,16w+16); O-acc c-rows [64w,64w+64) x all 64 i.
// K tile: double-buffered, async global_load_lds with pre-swizzled source.
// P tile: bf16 in LDS (stride 72 shorts), read directly as PV B-fragments.
__global__ __launch_bounds__(256) void attn(
    const short* __restrict__ qt, const short* __restrict__ kt,
    const short* __restrict__ vv, short* __restrict__ ot) {
  int itile = blockIdx.x, b = blockIdx.y;
  __shared__ short ktile[2][64 * 256];
  __shared__ short Pb[64 * 72];
  __shared__ float alpha_lds[64];
  __shared__ float lsum_lds[64];

  int t = threadIdx.x, w = t >> 6, lane = t & 63, g = lane >> 4, lr = lane & 15;
  int i0 = itile * 64;

  const short* ktg = kt + (size_t)b * NPIX * NC;
  const short* vg  = vv + (size_t)b * NC * NPIX;

  // prologue: issue async K loads for jt=0 into buffer 0
  for (int it = 0; it < 8; ++it) {
    int id = it * 256 + t, row = id >> 5, ch = id & 31;
    gload_lds16(&ktg[(size_t)row * 256 + (ch ^ (row & 7)) * 8],
                &ktile[0][id * 8]);
  }

  bf16x8 qf[8];
  {
    const short* qrow = qt + ((size_t)b * NPIX + i0 + w * 16 + lr) * NC;
    for (int ks = 0; ks < 8; ++ks)
      qf[ks] = *reinterpret_cast<const bf16x8*>(&qrow[ks * 32 + g * 8]);
  }

  f32x4 zz = {0.f, 0.f, 0.f, 0.f};
  f32x4 oacc[4][4];
  for (int i = 0; i < 4; ++i) for (int j = 0; j < 4; ++j) oacc[i][j] = zz;
  float m_[4], l_[4];
  for (int r = 0; r < 4; ++r) { m_[r] = -1e30f; l_[r] = 0.f; }

  const float sc = 0.0625f, L2E = 1.44269504f;
  const float SCL = sc * L2E;

  for (int jt = 0; jt < 64; ++jt) {
    int cur = jt & 1;
    // my K loads for buf[cur] complete; all waves past prior reads
    asm volatile("s_waitcnt vmcnt(0)" ::: "memory");
    __builtin_amdgcn_s_barrier();
    asm volatile("" ::: "memory");

    // issue next tile's loads into the other buffer (stay in flight across
    // the mid barrier — no vmcnt drain until next loop top)
    if (jt < 63) {
      const short* kg2 = ktg + (size_t)(jt + 1) * 64 * 256;
      short* lb = &ktile[cur ^ 1][0];
      for (int it = 0; it < 8; ++it) {
        int id = it * 256 + t, row = id >> 5, ch = id & 31;
        gload_lds16(&kg2[row * 256 + (ch ^ (row & 7)) * 8], &lb[id * 8]);
      }
    }

    // S = Q^T K  (rows 16w..16w+16, cols 0..63)
    f32x4 s[4];
    for (int nf = 0; nf < 4; ++nf) s[nf] = zz;
    const short* kts = &ktile[cur][0];
    for (int ks = 0; ks < 8; ++ks) {
      bf16x8 kf[4];
      for (int nf = 0; nf < 4; ++nf) {
        int row = nf * 16 + lr;
        kf[nf] = *reinterpret_cast<const bf16x8*>(
            &kts[row * 256 + (((ks * 4) + g) ^ (row & 7)) * 8]);
      }
      for (int nf = 0; nf < 4; ++nf) s[nf] = mfma16(qf[ks], kf[nf], s[nf]);
    }

    // online softmax (rows i_loc = 16w + 4g + r); P written as bf16
    float alpha[4];
    int prow = w * 16 + g * 4;
    for (int r = 0; r < 4; ++r) {
      float mx = fmaxf(fmaxf(s[0][r], s[1][r]), fmaxf(s[2][r], s[3][r]));
      for (int msk = 1; msk < 16; msk <<= 1) mx = fmaxf(mx, __shfl_xor(mx, msk));
      mx *= sc;
      float mn = fmaxf(m_[r], mx);
      alpha[r] = exp2f((m_[r] - mn) * L2E);
      float mnl = mn * L2E;
      float ps = 0.f;
      for (int nf = 0; nf < 4; ++nf) {
        float p = exp2f(fmaf(s[nf][r], SCL, -mnl));
        ps += p;
        Pb[(prow + r) * 72 + nf * 16 + lr] = f2bf(p);
      }
      for (int msk = 1; msk < 16; msk <<= 1) ps += __shfl_xor(ps, msk);
      l_[r] = l_[r] * alpha[r] + ps;
      m_[r] = mn;
    }
    if (lr == 0)
      for (int r = 0; r < 4; ++r) alpha_lds[prow + r] = alpha[r];

    // P/alpha visible to all waves; do NOT drain vmcnt (prefetch in flight)
    asm volatile("s_waitcnt lgkmcnt(0)" ::: "memory");
    __builtin_amdgcn_s_barrier();
    asm volatile("" ::: "memory");

    // rescale O, then O += V * P^T
    float av[4];
    for (int nf = 0; nf < 4; ++nf) av[nf] = alpha_lds[nf * 16 + lr];
    for (int mf = 0; mf < 4; ++mf)
      for (int nf = 0; nf < 4; ++nf) oacc[mf][nf] *= av[nf];

    for (int ks2 = 0; ks2 < 2; ++ks2) {
      bf16x8 va[4], pb[4];
      for (int mf = 0; mf < 4; ++mf)
        va[mf] = *reinterpret_cast<const bf16x8*>(
            &vg[(size_t)(w * 64 + mf * 16 + lr) * NPIX + jt * 64 + ks2 * 32 + g * 8]);
      for (int nf = 0; nf < 4; ++nf)
        pb[nf] = *reinterpret_cast<const bf16x8*>(
            &Pb[(nf * 16 + lr) * 72 + ks2 * 32 + g * 8]);
      for (int mf = 0; mf < 4; ++mf)
        for (int nf = 0; nf < 4; ++nf)
          oacc[mf][nf] = mfma16(va[mf], pb[nf], oacc[mf][nf]);
    }
  }

  if (lr == 0)
    for (int r = 0; r < 4; ++r) lsum_lds[w * 16 + g * 4 + r] = l_[r];
  __syncthreads();

  // write O^T: ot[b][i][c] bf16
  for (int nf = 0; nf < 4; ++nf) {
    float inv = 1.f / lsum_lds[nf * 16 + lr];
    int i = i0 + nf * 16 + lr;
    for (int mf = 0; mf < 4; ++mf) {
      int cb = w * 64 + mf * 16 + g * 4;
      s16x4 pk;
      for (int r = 0; r < 4; ++r) pk[r] = f2bf(oacc[mf][nf][r] * inv);
      *reinterpret_cast<s16x4*>(&ot[((size_t)b * NPIX + i) * NC + cb]) = pk;
    }
  }
}

// ---------------------------------------------------------------------------
// K4: proj + residual. out[b][o][n] = x + gamma*(sum_c wp[o][c]*O[c][n] + bp[o])
__global__ __launch_bounds__(256) void proj_res(
    const short* __restrict__ wp_bf, const float* __restrict__ bp,
    const short* __restrict__ ot, const float* __restrict__ x,
    const float* __restrict__ gamma, float* __restrict__ out) {
  int nt = blockIdx.x, b = blockIdx.y;
  __shared__ short otile[64 * 256];
  __shared__ float bias_lds[256];
  int t = threadIdx.x;
  const short* og = ot + ((size_t)b * NPIX + nt * 64) * NC;
  for (int itx = 0; itx < 8; ++itx) {
    int id = t + itx * 256, row = id >> 5, part = id & 31;
    *reinterpret_cast<uint4*>(&otile[row * 256 + (part ^ (row & 7)) * 8]) =
        *reinterpret_cast<const uint4*>(&og[(size_t)row * 256 + part * 8]);
  }
  bias_lds[t] = bp[t];
  __syncthreads();

  int w = t >> 6, lane = t & 63, g = lane >> 4, lr = lane & 15;
  f32x4 acc[4][4];
  f32x4 zz = {0.f, 0.f, 0.f, 0.f};
  for (int i = 0; i < 4; ++i) for (int j = 0; j < 4; ++j) acc[i][j] = zz;

  for (int c0 = 0; c0 < 256; c0 += 32) {
    bf16x8 af[4], bfr[4];
    for (int mf = 0; mf < 4; ++mf)
      af[mf] = *reinterpret_cast<const bf16x8*>(
          &wp_bf[(size_t)(w * 64 + mf * 16 + lr) * 256 + c0 + g * 8]);
    for (int nf = 0; nf < 4; ++nf) {
      int row = nf * 16 + lr;
      bfr[nf] = *reinterpret_cast<const bf16x8*>(
          &otile[row * 256 + (((c0 >> 3) + g) ^ (row & 7)) * 8]);
    }
    for (int mf = 0; mf < 4; ++mf)
      for (int nf = 0; nf < 4; ++nf)
        acc[mf][nf] = mfma16(af[mf], bfr[nf], acc[mf][nf]);
  }

  float gm = gamma[0];
  for (int mf = 0; mf < 4; ++mf)
    for (int nf = 0; nf < 4; ++nf) {
      int ob = w * 64 + mf * 16 + g * 4;
      int n  = nt * 64 + nf * 16 + lr;
      for (int r = 0; r < 4; ++r) {
        size_t idx = ((size_t)b * NC + ob + r) * NPIX + n;
        out[idx] = x[idx] + gm * (acc[mf][nf][r] + bias_lds[ob + r]);
      }
    }
}

// ---------------------------------------------------------------------------
extern "C" void kernel_launch(void* const* d_in, const int* in_sizes, int n_in,
                              void* d_out, int out_size, void* d_ws, size_t ws_size,
                              hipStream_t stream) {
  (void)in_sizes; (void)n_in; (void)out_size; (void)ws_size;
  const float* x     = (const float*)d_in[0];
  const float* gn_w  = (const float*)d_in[1];
  const float* gn_b  = (const float*)d_in[2];
  const float* wq    = (const float*)d_in[3];
  const float* bq    = (const float*)d_in[4];
  const float* wk    = (const float*)d_in[5];
  const float* bk    = (const float*)d_in[6];
  const float* wv    = (const float*)d_in[7];
  const float* bv    = (const float*)d_in[8];
  const float* wp    = (const float*)d_in[9];
  const float* bp    = (const float*)d_in[10];
  const float* gamma = (const float*)d_in[11];
  float* out = (float*)d_out;

  char* ws = (char*)d_ws;
  const size_t WSZ = 131072;            // 256*256*2B
  const size_t TSZ = (size_t)NB * NPIX * NC * 2;  // 16.78MB
  short* wq_bf = (short*)(ws);
  short* wk_bf = (short*)(ws + WSZ);
  short* wv_bf = (short*)(ws + 2 * WSZ);
  short* wp_bf = (short*)(ws + 3 * WSZ);
  short* xdt   = (short*)(ws + 4 * WSZ);            // reused as Ot after K2
  short* qt    = (short*)(ws + 4 * WSZ + TSZ);
  short* kt    = (short*)(ws + 4 * WSZ + 2 * TSZ);
  short* vv    = (short*)(ws + 4 * WSZ + 3 * TSZ);
  short* ot    = xdt;

  wconv<<<64, 256, 0, stream>>>(wq, wq_bf);
  wconv<<<64, 256, 0, stream>>>(wk, wk_bf);
  wconv<<<64, 256, 0, stream>>>(wv, wv_bf);
  wconv<<<64, 256, 0, stream>>>(wp, wp_bf);

  gnorm<<<256, 256, 0, stream>>>(x, gn_w, gn_b, xdt);

  qkv_gemm<<<dim3(64, 8, 3), 256, 0, stream>>>(wq_bf, wk_bf, wv_bf, bq, bk, bv,
                                               xdt, qt, kt, vv);

  attn<<<dim3(64, 8), 256, 0, stream>>>(qt, kt, vv, ot);

  proj_res<<<dim3(64, 8), 256, 0, stream>>>(wp_bf, bp, ot, x, gamma, out);
}

// Round 3
// 354.824 us; speedup vs baseline: 1.5673x; 1.5186x over previous
//
#include <hip/hip_runtime.h>
#include <cstdint>
#include <cstddef>

// ---------------------------------------------------------------------------
// SelfAttentionDiff: GN -> QKV (1x1) -> softmax(Q^T K/16) -> V P^T -> proj -> +res
// b=8, c=256, n=64*64=4096, groups=32 (8 ch/group)
// All GEMMs via v_mfma_f32_16x16x32_bf16, fp32 accumulation.
// Fragment conventions (verified r1: kernel passed with absmax 0.031):
//   A-frag: lane l holds A[mbase + (l&15)][kbase + 8*(l>>4) + e], e=0..7 (16B)
//   B-frag: lane l holds B[kbase + 8*(l>>4) + e][nbase + (l&15)]
//   D-frag: reg r -> row = 4*(l>>4)+r, col = (l&15)   [HW-verified m89]
// Attn uses SWAPPED QK^T: S^T[k][q] = mfma(A=K, B=Q) so each lane owns ONE
// q-row (col=lr) and 16 k-values (mf,r) -> in-register softmax.
// ---------------------------------------------------------------------------

#define NB   8
#define NC   256
#define NPIX 4096
#define CPG  8

typedef __attribute__((ext_vector_type(8))) short bf16x8;
typedef __attribute__((ext_vector_type(4))) short s16x4;
typedef __attribute__((ext_vector_type(8))) short s16x8;
typedef __attribute__((ext_vector_type(4))) float f32x4;

__device__ __forceinline__ short f2bf(float f) {
  union { float f; uint32_t u; } v; v.f = f;
  return (short)((v.u + 0x7fffu + ((v.u >> 16) & 1u)) >> 16);
}

__device__ __forceinline__ f32x4 mfma16(bf16x8 a, bf16x8 b, f32x4 c) {
  return __builtin_amdgcn_mfma_f32_16x16x32_bf16(a, b, c, 0, 0, 0);
}

__device__ __forceinline__ void gload_lds16(const short* g, short* l) {
  __builtin_amdgcn_global_load_lds(
      (const __attribute__((address_space(1))) void*)g,
      (__attribute__((address_space(3))) void*)l, 16, 0, 0);
}

// ---------------------------------------------------------------------------
// K0: fp32 -> bf16 convert for the 4 weight matrices (one launch)
__global__ __launch_bounds__(256) void wconv4(
    const float* __restrict__ w0, const float* __restrict__ w1,
    const float* __restrict__ w2, const float* __restrict__ w3,
    short* __restrict__ o0, short* __restrict__ o1,
    short* __restrict__ o2, short* __restrict__ o3) {
  int m = blockIdx.x >> 6;
  const float* w = (m == 0) ? w0 : (m == 1) ? w1 : (m == 2) ? w2 : w3;
  short* o = (m == 0) ? o0 : (m == 1) ? o1 : (m == 2) ? o2 : o3;
  int i = ((blockIdx.x & 63) * 256 + threadIdx.x) * 4;
  float4 v = *reinterpret_cast<const float4*>(w + i);
  s16x4 p;
  p[0] = f2bf(v.x); p[1] = f2bf(v.y); p[2] = f2bf(v.z); p[3] = f2bf(v.w);
  *reinterpret_cast<s16x4*>(o + i) = p;
}

// ---------------------------------------------------------------------------
// K1: GroupNorm. One block per (b,g). Writes x_dash transposed: xdt[b][pix][c] bf16.
__global__ __launch_bounds__(256) void gnorm(const float* __restrict__ x,
                                             const float* __restrict__ gw,
                                             const float* __restrict__ gb,
                                             short* __restrict__ xdt) {
  int b = blockIdx.x >> 5;
  int g = blockIdx.x & 31;
  const float* xp = x + ((size_t)b * NC + (size_t)g * CPG) * NPIX;
  int t = threadIdx.x;

  float s = 0.f, ss = 0.f;
  const float4* xp4 = reinterpret_cast<const float4*>(xp);
  for (int i = t; i < (CPG * NPIX) / 4; i += 256) {
    float4 v = xp4[i];
    s  += v.x + v.y + v.z + v.w;
    ss += v.x * v.x + v.y * v.y + v.z * v.z + v.w * v.w;
  }
  for (int m = 32; m; m >>= 1) { s += __shfl_xor(s, m); ss += __shfl_xor(ss, m); }
  __shared__ float red[10];
  int wid = t >> 6;
  if ((t & 63) == 0) { red[wid] = s; red[4 + wid] = ss; }
  __syncthreads();
  if (t == 0) {
    float a  = red[0] + red[1] + red[2] + red[3];
    float b2 = red[4] + red[5] + red[6] + red[7];
    float mean = a * (1.f / 32768.f);
    float var  = b2 * (1.f / 32768.f) - mean * mean;
    red[8] = mean;
    red[9] = rsqrtf(var + 1e-5f);
  }
  __syncthreads();
  float mean = red[8], rstd = red[9];

  float wv2[CPG], bv2[CPG];
  for (int cc = 0; cc < CPG; ++cc) {
    float wgt = gw[g * CPG + cc] * rstd;
    wv2[cc] = wgt;
    bv2[cc] = gb[g * CPG + cc] - mean * wgt;
  }
  for (int pix = t; pix < NPIX; pix += 256) {
    s16x8 pk;
    for (int cc = 0; cc < CPG; ++cc)
      pk[cc] = f2bf(fmaf(xp[cc * NPIX + pix], wv2[cc], bv2[cc]));
    *reinterpret_cast<s16x8*>(&xdt[((size_t)b * NPIX + pix) * NC + g * CPG]) = pk;
  }
}

// ---------------------------------------------------------------------------
// K2: QKV GEMM. grid(64 ntiles, 8 b, 3 mat). OUT[o][n] = sum_c W[o][c] xd[c][n] + bias.
// Q,K stored transposed [b][n][o]; V stored [b][o][n]. LDS tile XOR-swizzled (T2).
__global__ __launch_bounds__(256) void qkv_gemm(
    const short* __restrict__ wq_bf, const short* __restrict__ wk_bf,
    const short* __restrict__ wv_bf,
    const float* __restrict__ bq, const float* __restrict__ bk,
    const float* __restrict__ bv,
    const short* __restrict__ xdt,
    short* __restrict__ qt, short* __restrict__ kt, short* __restrict__ vv) {
  int nt = blockIdx.x, b = blockIdx.y, mi = blockIdx.z;
  const short* W; const float* bia;
  if (mi == 0)      { W = wq_bf; bia = bq; }
  else if (mi == 1) { W = wk_bf; bia = bk; }
  else              { W = wv_bf; bia = bv; }

  __shared__ short xtile[64 * 256];
  __shared__ float bias_lds[256];
  int t = threadIdx.x;
  const short* xg = xdt + ((size_t)b * NPIX + nt * 64) * NC;
  for (int it = 0; it < 8; ++it) {
    int id = t + it * 256, row = id >> 5, part = id & 31;
    *reinterpret_cast<uint4*>(&xtile[row * 256 + (part ^ (row & 7)) * 8]) =
        *reinterpret_cast<const uint4*>(&xg[(size_t)row * 256 + part * 8]);
  }
  bias_lds[t] = bia[t];
  __syncthreads();

  int w = t >> 6, lane = t & 63, g = lane >> 4, lr = lane & 15;
  f32x4 acc[4][4];
  f32x4 zz = {0.f, 0.f, 0.f, 0.f};
  for (int i = 0; i < 4; ++i) for (int j = 0; j < 4; ++j) acc[i][j] = zz;

  for (int c0 = 0; c0 < 256; c0 += 32) {
    bf16x8 af[4], bfr[4];
    for (int mf = 0; mf < 4; ++mf)
      af[mf] = *reinterpret_cast<const bf16x8*>(
          &W[(size_t)(w * 64 + mf * 16 + lr) * 256 + c0 + g * 8]);
    for (int nf = 0; nf < 4; ++nf) {
      int row = nf * 16 + lr;
      bfr[nf] = *reinterpret_cast<const bf16x8*>(
          &xtile[row * 256 + (((c0 >> 3) + g) ^ (row & 7)) * 8]);
    }
    for (int mf = 0; mf < 4; ++mf)
      for (int nf = 0; nf < 4; ++nf)
        acc[mf][nf] = mfma16(af[mf], bfr[nf], acc[mf][nf]);
  }

  if (mi < 2) {
    short* outp = (mi == 0) ? qt : kt;
    for (int mf = 0; mf < 4; ++mf)
      for (int nf = 0; nf < 4; ++nf) {
        int ob = w * 64 + mf * 16 + g * 4;
        int n  = nt * 64 + nf * 16 + lr;
        s16x4 pk;
        for (int r = 0; r < 4; ++r)
          pk[r] = f2bf(acc[mf][nf][r] + bias_lds[ob + r]);
        *reinterpret_cast<s16x4*>(&outp[((size_t)b * NPIX + n) * NC + ob]) = pk;
      }
  } else {
    for (int mf = 0; mf < 4; ++mf)
      for (int nf = 0; nf < 4; ++nf) {
        int ob = w * 64 + mf * 16 + g * 4;
        int n  = nt * 64 + nf * 16 + lr;
        for (int r = 0; r < 4; ++r)
          vv[((size_t)b * NC + ob + r) * NPIX + n] =
              f2bf(acc[mf][nf][r] + bias_lds[ob + r]);
      }
  }
}

// ---------------------------------------------------------------------------
// K3: flash attention, swapped-QK^T, in-register softmax.
// grid(64 itiles, 8 b), 4 waves. Wave w owns q-rows [16w,16w+16) for softmax;
// O-acc c-rows [64w,64w+64) x all 64 q. Each lane owns q = 16w+lr.
__global__ __launch_bounds__(256, 2) void attn(
    const short* __restrict__ qt, const short* __restrict__ kt,
    const short* __restrict__ vv, short* __restrict__ ot) {
  int itile = blockIdx.x, b = blockIdx.y;
  __shared__ short ktile[2][64 * 256];
  __shared__ short Pb[64 * 72];
  __shared__ float alpha_lds[64];
  __shared__ float lsum_lds[64];

  int t = threadIdx.x, w = t >> 6, lane = t & 63, g = lane >> 4, lr = lane & 15;
  int i0 = itile * 64;

  const short* ktg = kt + (size_t)b * NPIX * NC;
  const short* vg  = vv + (size_t)b * NC * NPIX;

  // prologue: async K loads for jt=0 into buffer 0
  for (int it = 0; it < 8; ++it) {
    int id = it * 256 + t, row = id >> 5, ch = id & 31;
    gload_lds16(&ktg[(size_t)row * 256 + (ch ^ (row & 7)) * 8],
                &ktile[0][id * 8]);
  }

  bf16x8 qf[8];
  {
    const short* qrow = qt + ((size_t)b * NPIX + i0 + w * 16 + lr) * NC;
    for (int ks = 0; ks < 8; ++ks)
      qf[ks] = *reinterpret_cast<const bf16x8*>(&qrow[ks * 32 + g * 8]);
  }

  f32x4 zz = {0.f, 0.f, 0.f, 0.f};
  f32x4 oacc[4][4];
  for (int i = 0; i < 4; ++i) for (int j = 0; j < 4; ++j) oacc[i][j] = zz;
  float m_ = -1e30f, l_ = 0.f;

  const float sc = 0.0625f, L2E = 1.44269504f;
  const float SCL = sc * L2E;

  for (int jt = 0; jt < 64; ++jt) {
    int cur = jt & 1;

    // V fragments for THIS tile, issued before prefetch so waits on V don't
    // drain the K-prefetch queue. Latency hides under QK^T + softmax.
    bf16x8 va[2][4];
    for (int ks2 = 0; ks2 < 2; ++ks2)
      for (int mf = 0; mf < 4; ++mf)
        va[ks2][mf] = *reinterpret_cast<const bf16x8*>(
            &vg[(size_t)(w * 64 + mf * 16 + lr) * NPIX + jt * 64 + ks2 * 32 + g * 8]);

    // K tile for this iteration complete (own DMA), all waves synced
    asm volatile("s_waitcnt vmcnt(0)" ::: "memory");
    __builtin_amdgcn_s_barrier();
    asm volatile("" ::: "memory");

    // prefetch next K tile into other buffer (in flight across mid barrier)
    if (jt < 63) {
      const short* kg2 = ktg + (size_t)(jt + 1) * 64 * 256;
      short* lb = &ktile[cur ^ 1][0];
      for (int it = 0; it < 8; ++it) {
        int id = it * 256 + t, row = id >> 5, ch = id & 31;
        gload_lds16(&kg2[row * 256 + (ch ^ (row & 7)) * 8], &lb[id * 8]);
      }
    }

    // S^T = K Q^T: s[mf] rows k = mf*16+4g+r, col q = w*16+lr
    f32x4 s[4];
    for (int mf = 0; mf < 4; ++mf) s[mf] = zz;
    const short* kts = &ktile[cur][0];
    for (int ks = 0; ks < 8; ++ks) {
      bf16x8 kf[4];
      for (int mf = 0; mf < 4; ++mf) {
        int row = mf * 16 + lr;
        kf[mf] = *reinterpret_cast<const bf16x8*>(
            &kts[row * 256 + (((ks * 4) + g) ^ (row & 7)) * 8]);
      }
      for (int mf = 0; mf < 4; ++mf) s[mf] = mfma16(kf[mf], qf[ks], s[mf]);
    }

    // in-register online softmax for my q-row (4 redundant lane copies per q)
    float mx = s[0][0];
    for (int mf = 0; mf < 4; ++mf)
      for (int r = 0; r < 4; ++r) mx = fmaxf(mx, s[mf][r]);
    mx = fmaxf(mx, __shfl_xor(mx, 16));
    mx = fmaxf(mx, __shfl_xor(mx, 32));
    float pm = mx * sc;
    // defer-max: keep old m when growth <= 8 (alpha == 1 exactly)
    float mn = (pm - m_ <= 8.f) ? m_ : pm;
    float alpha = exp2f((m_ - mn) * L2E);
    float mnl = mn * L2E;
    float ps = 0.f;
    int q_loc = w * 16 + lr;
    for (int mf = 0; mf < 4; ++mf) {
      s16x4 pk;
      for (int r = 0; r < 4; ++r) {
        float p = exp2f(fmaf(s[mf][r], SCL, -mnl));
        ps += p;
        pk[r] = f2bf(p);
      }
      *reinterpret_cast<s16x4*>(&Pb[q_loc * 72 + mf * 16 + g * 4]) = pk;
    }
    ps += __shfl_xor(ps, 16);
    ps += __shfl_xor(ps, 32);
    l_ = l_ * alpha + ps;
    m_ = mn;
    if (lane < 16) alpha_lds[w * 16 + lane] = alpha;

    // P/alpha visible; vmcnt NOT drained (prefetch stays in flight)
    asm volatile("s_waitcnt lgkmcnt(0)" ::: "memory");
    __builtin_amdgcn_s_barrier();
    asm volatile("" ::: "memory");

    // rescale O only if some alpha != 1 (defer-max makes this rare)
    float av[4];
    for (int nf = 0; nf < 4; ++nf) av[nf] = alpha_lds[nf * 16 + lr];
    if (__any((av[0] != 1.f) | (av[1] != 1.f) | (av[2] != 1.f) | (av[3] != 1.f))) {
      for (int mf = 0; mf < 4; ++mf)
        for (int nf = 0; nf < 4; ++nf) oacc[mf][nf] *= av[nf];
    }

    // O += V P^T
    for (int ks2 = 0; ks2 < 2; ++ks2) {
      bf16x8 pb[4];
      for (int nf = 0; nf < 4; ++nf)
        pb[nf] = *reinterpret_cast<const bf16x8*>(
            &Pb[(nf * 16 + lr) * 72 + ks2 * 32 + g * 8]);
      for (int mf = 0; mf < 4; ++mf)
        for (int nf = 0; nf < 4; ++nf)
          oacc[mf][nf] = mfma16(va[ks2][mf], pb[nf], oacc[mf][nf]);
    }
  }

  if (lane < 16) lsum_lds[w * 16 + lane] = l_;
  __syncthreads();

  // write O^T: ot[b][i][c] bf16
  for (int nf = 0; nf < 4; ++nf) {
    float inv = 1.f / lsum_lds[nf * 16 + lr];
    int i = i0 + nf * 16 + lr;
    for (int mf = 0; mf < 4; ++mf) {
      int cb = w * 64 + mf * 16 + g * 4;
      s16x4 pk;
      for (int r = 0; r < 4; ++r) pk[r] = f2bf(oacc[mf][nf][r] * inv);
      *reinterpret_cast<s16x4*>(&ot[((size_t)b * NPIX + i) * NC + cb]) = pk;
    }
  }
}

// ---------------------------------------------------------------------------
// K4: proj + residual. out[b][o][n] = x + gamma*(sum_c wp[o][c]*O[c][n] + bp[o])
__global__ __launch_bounds__(256) void proj_res(
    const short* __restrict__ wp_bf, const float* __restrict__ bp,
    const short* __restrict__ ot, const float* __restrict__ x,
    const float* __restrict__ gamma, float* __restrict__ out) {
  int nt = blockIdx.x, b = blockIdx.y;
  __shared__ short otile[64 * 256];
  __shared__ float bias_lds[256];
  int t = threadIdx.x;
  const short* og = ot + ((size_t)b * NPIX + nt * 64) * NC;
  for (int itx = 0; itx < 8; ++itx) {
    int id = t + itx * 256, row = id >> 5, part = id & 31;
    *reinterpret_cast<uint4*>(&otile[row * 256 + (part ^ (row & 7)) * 8]) =
        *reinterpret_cast<const uint4*>(&og[(size_t)row * 256 + part * 8]);
  }
  bias_lds[t] = bp[t];
  __syncthreads();

  int w = t >> 6, lane = t & 63, g = lane >> 4, lr = lane & 15;
  f32x4 acc[4][4];
  f32x4 zz = {0.f, 0.f, 0.f, 0.f};
  for (int i = 0; i < 4; ++i) for (int j = 0; j < 4; ++j) acc[i][j] = zz;

  for (int c0 = 0; c0 < 256; c0 += 32) {
    bf16x8 af[4], bfr[4];
    for (int mf = 0; mf < 4; ++mf)
      af[mf] = *reinterpret_cast<const bf16x8*>(
          &wp_bf[(size_t)(w * 64 + mf * 16 + lr) * 256 + c0 + g * 8]);
    for (int nf = 0; nf < 4; ++nf) {
      int row = nf * 16 + lr;
      bfr[nf] = *reinterpret_cast<const bf16x8*>(
          &otile[row * 256 + (((c0 >> 3) + g) ^ (row & 7)) * 8]);
    }
    for (int mf = 0; mf < 4; ++mf)
      for (int nf = 0; nf < 4; ++nf)
        acc[mf][nf] = mfma16(af[mf], bfr[nf], acc[mf][nf]);
  }

  float gm = gamma[0];
  for (int mf = 0; mf < 4; ++mf)
    for (int nf = 0; nf < 4; ++nf) {
      int ob = w * 64 + mf * 16 + g * 4;
      int n  = nt * 64 + nf * 16 + lr;
      for (int r = 0; r < 4; ++r) {
        size_t idx = ((size_t)b * NC + ob + r) * NPIX + n;
        out[idx] = x[idx] + gm * (acc[mf][nf][r] + bias_lds[ob + r]);
      }
    }
}

// ---------------------------------------------------------------------------
extern "C" void kernel_launch(void* const* d_in, const int* in_sizes, int n_in,
                              void* d_out, int out_size, void* d_ws, size_t ws_size,
                              hipStream_t stream) {
  (void)in_sizes; (void)n_in; (void)out_size; (void)ws_size;
  const float* x     = (const float*)d_in[0];
  const float* gn_w  = (const float*)d_in[1];
  const float* gn_b  = (const float*)d_in[2];
  const float* wq    = (const float*)d_in[3];
  const float* bq    = (const float*)d_in[4];
  const float* wk    = (const float*)d_in[5];
  const float* bk    = (const float*)d_in[6];
  const float* wv    = (const float*)d_in[7];
  const float* bv    = (const float*)d_in[8];
  const float* wp    = (const float*)d_in[9];
  const float* bp    = (const float*)d_in[10];
  const float* gamma = (const float*)d_in[11];
  float* out = (float*)d_out;

  char* ws = (char*)d_ws;
  const size_t WSZ = 131072;                      // 256*256*2B
  const size_t TSZ = (size_t)NB * NPIX * NC * 2;  // 16.78MB
  short* wq_bf = (short*)(ws);
  short* wk_bf = (short*)(ws + WSZ);
  short* wv_bf = (short*)(ws + 2 * WSZ);
  short* wp_bf = (short*)(ws + 3 * WSZ);
  short* xdt   = (short*)(ws + 4 * WSZ);          // reused as Ot after K2
  short* qt    = (short*)(ws + 4 * WSZ + TSZ);
  short* kt    = (short*)(ws + 4 * WSZ + 2 * TSZ);
  short* vv    = (short*)(ws + 4 * WSZ + 3 * TSZ);
  short* ot    = xdt;

  wconv4<<<256, 256, 0, stream>>>(wq, wk, wv, wp, wq_bf, wk_bf, wv_bf, wp_bf);

  gnorm<<<256, 256, 0, stream>>>(x, gn_w, gn_b, xdt);

  qkv_gemm<<<dim3(64, 8, 3), 256, 0, stream>>>(wq_bf, wk_bf, wv_bf, bq, bk, bv,
                                               xdt, qt, kt, vv);

  attn<<<dim3(64, 8), 256, 0, stream>>>(qt, kt, vv, ot);

  proj_res<<<dim3(64, 8), 256, 0, stream>>>(wp_bf, bp, ot, x, gamma, out);
}

// Round 4
// 309.325 us; speedup vs baseline: 1.7979x; 1.1471x over previous
//
#include <hip/hip_runtime.h>
#include <cstdint>
#include <cstddef>

// ---------------------------------------------------------------------------
// SelfAttentionDiff: GN -> QKV (1x1) -> softmax(Q^T K/16) -> V P^T -> proj -> +res
// b=8, c=256, n=64*64=4096, groups=32 (8 ch/group)
// All GEMMs via v_mfma_f32_16x16x32_bf16, fp32 accumulation.
// Fragment conventions (verified r1-r3, absmax 0.031):
//   A-frag: lane l holds A[mbase + (l&15)][kbase + 8*(l>>4) + e], e=0..7 (16B)
//   B-frag: lane l holds B[kbase + 8*(l>>4) + e][nbase + (l&15)]
//   D-frag: reg r -> row = 4*(l>>4)+r, col = (l&15)   [HW-verified m89]
// Attn: SWAPPED QK^T (mfma(K,Q)) -> lane owns one q-row -> in-register softmax.
// Pipeline: counted vmcnt(8) only (T4), V-latency hidden under QK+softmax,
// K-DMA double-buffered across iterations, setprio around MFMA (T5).
// ---------------------------------------------------------------------------

#define NB   8
#define NC   256
#define NPIX 4096
#define CPG  8

typedef __attribute__((ext_vector_type(8))) short bf16x8;
typedef __attribute__((ext_vector_type(4))) short s16x4;
typedef __attribute__((ext_vector_type(8))) short s16x8;
typedef __attribute__((ext_vector_type(4))) float f32x4;

__device__ __forceinline__ short f2bf(float f) {
  union { float f; uint32_t u; } v; v.f = f;
  return (short)((v.u + 0x7fffu + ((v.u >> 16) & 1u)) >> 16);
}

__device__ __forceinline__ uint32_t cvtpk_bf(float a, float b) {
  uint32_t r;
  asm("v_cvt_pk_bf16_f32 %0, %1, %2" : "=v"(r) : "v"(a), "v"(b));
  return r;
}

__device__ __forceinline__ f32x4 mfma16(bf16x8 a, bf16x8 b, f32x4 c) {
  return __builtin_amdgcn_mfma_f32_16x16x32_bf16(a, b, c, 0, 0, 0);
}

__device__ __forceinline__ void gload_lds16(const short* g, short* l) {
  __builtin_amdgcn_global_load_lds(
      (const __attribute__((address_space(1))) void*)g,
      (__attribute__((address_space(3))) void*)l, 16, 0, 0);
}

// ---------------------------------------------------------------------------
// K0: fp32 -> bf16 convert for the 4 weight matrices (one launch)
__global__ __launch_bounds__(256) void wconv4(
    const float* __restrict__ w0, const float* __restrict__ w1,
    const float* __restrict__ w2, const float* __restrict__ w3,
    short* __restrict__ o0, short* __restrict__ o1,
    short* __restrict__ o2, short* __restrict__ o3) {
  int m = blockIdx.x >> 6;
  const float* w = (m == 0) ? w0 : (m == 1) ? w1 : (m == 2) ? w2 : w3;
  short* o = (m == 0) ? o0 : (m == 1) ? o1 : (m == 2) ? o2 : o3;
  int i = ((blockIdx.x & 63) * 256 + threadIdx.x) * 4;
  float4 v = *reinterpret_cast<const float4*>(w + i);
  s16x4 p;
  p[0] = f2bf(v.x); p[1] = f2bf(v.y); p[2] = f2bf(v.z); p[3] = f2bf(v.w);
  *reinterpret_cast<s16x4*>(o + i) = p;
}

// ---------------------------------------------------------------------------
// K1: GroupNorm. One block per (b,g). Writes x_dash transposed: xdt[b][pix][c] bf16.
__global__ __launch_bounds__(256) void gnorm(const float* __restrict__ x,
                                             const float* __restrict__ gw,
                                             const float* __restrict__ gb,
                                             short* __restrict__ xdt) {
  int b = blockIdx.x >> 5;
  int g = blockIdx.x & 31;
  const float* xp = x + ((size_t)b * NC + (size_t)g * CPG) * NPIX;
  int t = threadIdx.x;

  float s = 0.f, ss = 0.f;
  const float4* xp4 = reinterpret_cast<const float4*>(xp);
  for (int i = t; i < (CPG * NPIX) / 4; i += 256) {
    float4 v = xp4[i];
    s  += v.x + v.y + v.z + v.w;
    ss += v.x * v.x + v.y * v.y + v.z * v.z + v.w * v.w;
  }
  for (int m = 32; m; m >>= 1) { s += __shfl_xor(s, m); ss += __shfl_xor(ss, m); }
  __shared__ float red[10];
  int wid = t >> 6;
  if ((t & 63) == 0) { red[wid] = s; red[4 + wid] = ss; }
  __syncthreads();
  if (t == 0) {
    float a  = red[0] + red[1] + red[2] + red[3];
    float b2 = red[4] + red[5] + red[6] + red[7];
    float mean = a * (1.f / 32768.f);
    float var  = b2 * (1.f / 32768.f) - mean * mean;
    red[8] = mean;
    red[9] = rsqrtf(var + 1e-5f);
  }
  __syncthreads();
  float mean = red[8], rstd = red[9];

  float wv2[CPG], bv2[CPG];
  for (int cc = 0; cc < CPG; ++cc) {
    float wgt = gw[g * CPG + cc] * rstd;
    wv2[cc] = wgt;
    bv2[cc] = gb[g * CPG + cc] - mean * wgt;
  }
  for (int pix = t; pix < NPIX; pix += 256) {
    s16x8 pk;
    for (int cc = 0; cc < CPG; ++cc)
      pk[cc] = f2bf(fmaf(xp[cc * NPIX + pix], wv2[cc], bv2[cc]));
    *reinterpret_cast<s16x8*>(&xdt[((size_t)b * NPIX + pix) * NC + g * CPG]) = pk;
  }
}

// ---------------------------------------------------------------------------
// K2: QKV GEMM. grid(64 ntiles, 8 b, 3 mat). OUT[o][n] = sum_c W[o][c] xd[c][n] + bias.
// Q,K stored transposed [b][n][o]; V stored [b][o][n]. LDS tile XOR-swizzled (T2).
__global__ __launch_bounds__(256) void qkv_gemm(
    const short* __restrict__ wq_bf, const short* __restrict__ wk_bf,
    const short* __restrict__ wv_bf,
    const float* __restrict__ bq, const float* __restrict__ bk,
    const float* __restrict__ bv,
    const short* __restrict__ xdt,
    short* __restrict__ qt, short* __restrict__ kt, short* __restrict__ vv) {
  int nt = blockIdx.x, b = blockIdx.y, mi = blockIdx.z;
  const short* W; const float* bia;
  if (mi == 0)      { W = wq_bf; bia = bq; }
  else if (mi == 1) { W = wk_bf; bia = bk; }
  else              { W = wv_bf; bia = bv; }

  __shared__ short xtile[64 * 256];
  __shared__ float bias_lds[256];
  int t = threadIdx.x;
  const short* xg = xdt + ((size_t)b * NPIX + nt * 64) * NC;
  for (int it = 0; it < 8; ++it) {
    int id = t + it * 256, row = id >> 5, part = id & 31;
    *reinterpret_cast<uint4*>(&xtile[row * 256 + (part ^ (row & 7)) * 8]) =
        *reinterpret_cast<const uint4*>(&xg[(size_t)row * 256 + part * 8]);
  }
  bias_lds[t] = bia[t];
  __syncthreads();

  int w = t >> 6, lane = t & 63, g = lane >> 4, lr = lane & 15;
  f32x4 acc[4][4];
  f32x4 zz = {0.f, 0.f, 0.f, 0.f};
  for (int i = 0; i < 4; ++i) for (int j = 0; j < 4; ++j) acc[i][j] = zz;

  for (int c0 = 0; c0 < 256; c0 += 32) {
    bf16x8 af[4], bfr[4];
    for (int mf = 0; mf < 4; ++mf)
      af[mf] = *reinterpret_cast<const bf16x8*>(
          &W[(size_t)(w * 64 + mf * 16 + lr) * 256 + c0 + g * 8]);
    for (int nf = 0; nf < 4; ++nf) {
      int row = nf * 16 + lr;
      bfr[nf] = *reinterpret_cast<const bf16x8*>(
          &xtile[row * 256 + (((c0 >> 3) + g) ^ (row & 7)) * 8]);
    }
    for (int mf = 0; mf < 4; ++mf)
      for (int nf = 0; nf < 4; ++nf)
        acc[mf][nf] = mfma16(af[mf], bfr[nf], acc[mf][nf]);
  }

  if (mi < 2) {
    short* outp = (mi == 0) ? qt : kt;
    for (int mf = 0; mf < 4; ++mf)
      for (int nf = 0; nf < 4; ++nf) {
        int ob = w * 64 + mf * 16 + g * 4;
        int n  = nt * 64 + nf * 16 + lr;
        s16x4 pk;
        for (int r = 0; r < 4; ++r)
          pk[r] = f2bf(acc[mf][nf][r] + bias_lds[ob + r]);
        *reinterpret_cast<s16x4*>(&outp[((size_t)b * NPIX + n) * NC + ob]) = pk;
      }
  } else {
    for (int mf = 0; mf < 4; ++mf)
      for (int nf = 0; nf < 4; ++nf) {
        int ob = w * 64 + mf * 16 + g * 4;
        int n  = nt * 64 + nf * 16 + lr;
        for (int r = 0; r < 4; ++r)
          vv[((size_t)b * NC + ob + r) * NPIX + n] =
              f2bf(acc[mf][nf][r] + bias_lds[ob + r]);
      }
  }
}

// ---------------------------------------------------------------------------
// K3: flash attention, swapped-QK^T, in-register softmax, counted-vmcnt pipeline.
// grid(8 b, 64 itiles) -> each XCD gets one batch's blocks (K/V L2-resident).
// Block: 4 waves. Wave w owns q-rows [16w,16w+16); O-acc c-rows [64w,64w+64).
__global__ __launch_bounds__(256, 2) void attn(
    const short* __restrict__ qt, const short* __restrict__ kt,
    const short* __restrict__ vv, short* __restrict__ ot) {
  int b = blockIdx.x, itile = blockIdx.y;
  __shared__ short ktile[2][64 * 256];
  __shared__ short Pb[64 * 72];
  __shared__ float alpha_lds[64];
  __shared__ float lsum_lds[64];

  int t = threadIdx.x, w = t >> 6, lane = t & 63, g = lane >> 4, lr = lane & 15;
  int i0 = itile * 64;

  const short* ktg = kt + (size_t)b * NPIX * NC;
  const short* vg  = vv + (size_t)b * NC * NPIX;

  // prologue: async K-DMA for jt=0 into buffer 0
  for (int it = 0; it < 8; ++it) {
    int id = it * 256 + t, row = id >> 5, ch = id & 31;
    gload_lds16(&ktg[(size_t)row * 256 + (ch ^ (row & 7)) * 8],
                &ktile[0][id * 8]);
  }

  bf16x8 qf[8];
  {
    const short* qrow = qt + ((size_t)b * NPIX + i0 + w * 16 + lr) * NC;
    for (int ks = 0; ks < 8; ++ks)
      qf[ks] = *reinterpret_cast<const bf16x8*>(&qrow[ks * 32 + g * 8]);
  }

  f32x4 zz = {0.f, 0.f, 0.f, 0.f};
  f32x4 oacc[4][4];
  for (int i = 0; i < 4; ++i) for (int j = 0; j < 4; ++j) oacc[i][j] = zz;
  float m_ = -1e30f, l_ = 0.f;

  const float sc = 0.0625f, L2E = 1.44269504f;
  const float SCL = sc * L2E;

  for (int jt = 0; jt < 64; ++jt) {
    int cur = jt & 1;

    // V fragments for THIS tile (latency hides under QK^T + softmax; drained
    // by the vmcnt(8) before PV, not here)
    bf16x8 va[2][4];
    for (int ks2 = 0; ks2 < 2; ++ks2)
      for (int mf = 0; mf < 4; ++mf)
        va[ks2][mf] = *reinterpret_cast<const bf16x8*>(
            &vg[(size_t)(w * 64 + mf * 16 + lr) * NPIX + jt * 64 + ks2 * 32 + g * 8]);

    // wait for my K-DMA of THIS tile only (V loads stay in flight)
    asm volatile("s_waitcnt vmcnt(8)" ::: "memory");
    __builtin_amdgcn_s_barrier();
    asm volatile("" ::: "memory");

    // prefetch next K tile (jt=63 wraps to tile 0: uniform vmcnt counts)
    {
      const short* kg2 = ktg + (size_t)((jt + 1) & 63) * 64 * 256;
      short* lb = &ktile[cur ^ 1][0];
      for (int it = 0; it < 8; ++it) {
        int id = it * 256 + t, row = id >> 5, ch = id & 31;
        gload_lds16(&kg2[row * 256 + (ch ^ (row & 7)) * 8], &lb[id * 8]);
      }
    }

    // S^T = K Q^T: s[mf] rows k = mf*16+4g+r, col q = w*16+lr
    f32x4 s[4];
    for (int mf = 0; mf < 4; ++mf) s[mf] = zz;
    const short* kts = &ktile[cur][0];
    __builtin_amdgcn_s_setprio(1);
    for (int ks = 0; ks < 8; ++ks) {
      bf16x8 kf[4];
      for (int mf = 0; mf < 4; ++mf) {
        int row = mf * 16 + lr;
        kf[mf] = *reinterpret_cast<const bf16x8*>(
            &kts[row * 256 + (((ks * 4) + g) ^ (row & 7)) * 8]);
      }
      for (int mf = 0; mf < 4; ++mf) s[mf] = mfma16(kf[mf], qf[ks], s[mf]);
    }
    __builtin_amdgcn_s_setprio(0);

    // in-register online softmax for my q-row
    float mx = s[0][0];
    for (int mf = 0; mf < 4; ++mf)
      for (int r = 0; r < 4; ++r) mx = fmaxf(mx, s[mf][r]);
    mx = fmaxf(mx, __shfl_xor(mx, 16));
    mx = fmaxf(mx, __shfl_xor(mx, 32));
    float pm = mx * sc;
    // defer-max: keep old m when growth <= 8 (alpha == 1 exactly)
    float mn = (pm - m_ <= 8.f) ? m_ : pm;
    float alpha = exp2f((m_ - mn) * L2E);
    float mnl = mn * L2E;
    float ps = 0.f;
    int q_loc = w * 16 + lr;
    for (int mf = 0; mf < 4; ++mf) {
      float p0 = exp2f(fmaf(s[mf][0], SCL, -mnl));
      float p1 = exp2f(fmaf(s[mf][1], SCL, -mnl));
      float p2 = exp2f(fmaf(s[mf][2], SCL, -mnl));
      float p3 = exp2f(fmaf(s[mf][3], SCL, -mnl));
      ps += p0 + p1 + p2 + p3;
      uint2 pk;
      pk.x = cvtpk_bf(p0, p1);
      pk.y = cvtpk_bf(p2, p3);
      *reinterpret_cast<uint2*>(&Pb[q_loc * 72 + mf * 16 + g * 4]) = pk;
    }
    ps += __shfl_xor(ps, 16);
    ps += __shfl_xor(ps, 32);
    l_ = l_ * alpha + ps;
    m_ = mn;
    if (lane < 16) alpha_lds[w * 16 + lane] = alpha;

    // P/alpha visible; K-prefetch stays in flight
    asm volatile("s_waitcnt lgkmcnt(0)" ::: "memory");
    __builtin_amdgcn_s_barrier();
    asm volatile("" ::: "memory");

    // drain V (8 oldest), keep K-prefetch (8 newest) in flight
    asm volatile("s_waitcnt vmcnt(8)" ::: "memory");

    // rescale O only if some alpha != 1 (defer-max makes this rare)
    float av[4];
    for (int nf = 0; nf < 4; ++nf) av[nf] = alpha_lds[nf * 16 + lr];
    if (__any((av[0] != 1.f) | (av[1] != 1.f) | (av[2] != 1.f) | (av[3] != 1.f))) {
      for (int mf = 0; mf < 4; ++mf)
        for (int nf = 0; nf < 4; ++nf) oacc[mf][nf] *= av[nf];
    }

    // O += V P^T
    __builtin_amdgcn_s_setprio(1);
    for (int ks2 = 0; ks2 < 2; ++ks2) {
      bf16x8 pb[4];
      for (int nf = 0; nf < 4; ++nf)
        pb[nf] = *reinterpret_cast<const bf16x8*>(
            &Pb[(nf * 16 + lr) * 72 + ks2 * 32 + g * 8]);
      for (int mf = 0; mf < 4; ++mf)
        for (int nf = 0; nf < 4; ++nf)
          oacc[mf][nf] = mfma16(va[ks2][mf], pb[nf], oacc[mf][nf]);
    }
    __builtin_amdgcn_s_setprio(0);
  }

  if (lane < 16) lsum_lds[w * 16 + lane] = l_;
  __syncthreads();

  // write O^T: ot[b][i][c] bf16
  for (int nf = 0; nf < 4; ++nf) {
    float inv = 1.f / lsum_lds[nf * 16 + lr];
    int i = i0 + nf * 16 + lr;
    for (int mf = 0; mf < 4; ++mf) {
      int cb = w * 64 + mf * 16 + g * 4;
      s16x4 pk;
      for (int r = 0; r < 4; ++r) pk[r] = f2bf(oacc[mf][nf][r] * inv);
      *reinterpret_cast<s16x4*>(&ot[((size_t)b * NPIX + i) * NC + cb]) = pk;
    }
  }
}

// ---------------------------------------------------------------------------
// K4: proj + residual. out[b][o][n] = x + gamma*(sum_c wp[o][c]*O[c][n] + bp[o])
__global__ __launch_bounds__(256) void proj_res(
    const short* __restrict__ wp_bf, const float* __restrict__ bp,
    const short* __restrict__ ot, const float* __restrict__ x,
    const float* __restrict__ gamma, float* __restrict__ out) {
  int nt = blockIdx.x, b = blockIdx.y;
  __shared__ short otile[64 * 256];
  __shared__ float bias_lds[256];
  int t = threadIdx.x;
  const short* og = ot + ((size_t)b * NPIX + nt * 64) * NC;
  for (int itx = 0; itx < 8; ++itx) {
    int id = t + itx * 256, row = id >> 5, part = id & 31;
    *reinterpret_cast<uint4*>(&otile[row * 256 + (part ^ (row & 7)) * 8]) =
        *reinterpret_cast<const uint4*>(&og[(size_t)row * 256 + part * 8]);
  }
  bias_lds[t] = bp[t];
  __syncthreads();

  int w = t >> 6, lane = t & 63, g = lane >> 4, lr = lane & 15;
  f32x4 acc[4][4];
  f32x4 zz = {0.f, 0.f, 0.f, 0.f};
  for (int i = 0; i < 4; ++i) for (int j = 0; j < 4; ++j) acc[i][j] = zz;

  for (int c0 = 0; c0 < 256; c0 += 32) {
    bf16x8 af[4], bfr[4];
    for (int mf = 0; mf < 4; ++mf)
      af[mf] = *reinterpret_cast<const bf16x8*>(
          &wp_bf[(size_t)(w * 64 + mf * 16 + lr) * 256 + c0 + g * 8]);
    for (int nf = 0; nf < 4; ++nf) {
      int row = nf * 16 + lr;
      bfr[nf] = *reinterpret_cast<const bf16x8*>(
          &otile[row * 256 + (((c0 >> 3) + g) ^ (row & 7)) * 8]);
    }
    for (int mf = 0; mf < 4; ++mf)
      for (int nf = 0; nf < 4; ++nf)
        acc[mf][nf] = mfma16(af[mf], bfr[nf], acc[mf][nf]);
  }

  float gm = gamma[0];
  for (int mf = 0; mf < 4; ++mf)
    for (int nf = 0; nf < 4; ++nf) {
      int ob = w * 64 + mf * 16 + g * 4;
      int n  = nt * 64 + nf * 16 + lr;
      for (int r = 0; r < 4; ++r) {
        size_t idx = ((size_t)b * NC + ob + r) * NPIX + n;
        out[idx] = x[idx] + gm * (acc[mf][nf][r] + bias_lds[ob + r]);
      }
    }
}

// ---------------------------------------------------------------------------
extern "C" void kernel_launch(void* const* d_in, const int* in_sizes, int n_in,
                              void* d_out, int out_size, void* d_ws, size_t ws_size,
                              hipStream_t stream) {
  (void)in_sizes; (void)n_in; (void)out_size; (void)ws_size;
  const float* x     = (const float*)d_in[0];
  const float* gn_w  = (const float*)d_in[1];
  const float* gn_b  = (const float*)d_in[2];
  const float* wq    = (const float*)d_in[3];
  const float* bq    = (const float*)d_in[4];
  const float* wk    = (const float*)d_in[5];
  const float* bk    = (const float*)d_in[6];
  const float* wv    = (const float*)d_in[7];
  const float* bv    = (const float*)d_in[8];
  const float* wp    = (const float*)d_in[9];
  const float* bp    = (const float*)d_in[10];
  const float* gamma = (const float*)d_in[11];
  float* out = (float*)d_out;

  char* ws = (char*)d_ws;
  const size_t WSZ = 131072;                      // 256*256*2B
  const size_t TSZ = (size_t)NB * NPIX * NC * 2;  // 16.78MB
  short* wq_bf = (short*)(ws);
  short* wk_bf = (short*)(ws + WSZ);
  short* wv_bf = (short*)(ws + 2 * WSZ);
  short* wp_bf = (short*)(ws + 3 * WSZ);
  short* xdt   = (short*)(ws + 4 * WSZ);          // reused as Ot after K2
  short* qt    = (short*)(ws + 4 * WSZ + TSZ);
  short* kt    = (short*)(ws + 4 * WSZ + 2 * TSZ);
  short* vv    = (short*)(ws + 4 * WSZ + 3 * TSZ);
  short* ot    = xdt;

  wconv4<<<256, 256, 0, stream>>>(wq, wk, wv, wp, wq_bf, wk_bf, wv_bf, wp_bf);

  gnorm<<<256, 256, 0, stream>>>(x, gn_w, gn_b, xdt);

  qkv_gemm<<<dim3(64, 8, 3), 256, 0, stream>>>(wq_bf, wk_bf, wv_bf, bq, bk, bv,
                                               xdt, qt, kt, vv);

  attn<<<dim3(8, 64), 256, 0, stream>>>(qt, kt, vv, ot);

  proj_res<<<dim3(64, 8), 256, 0, stream>>>(wp_bf, bp, ot, x, gamma, out);
}

// Round 5
// 307.074 us; speedup vs baseline: 1.8111x; 1.0073x over previous
//
#include <hip/hip_runtime.h>
#include <cstdint>
#include <cstddef>

// ---------------------------------------------------------------------------
// SelfAttentionDiff: GN -> QKV (1x1) -> softmax(Q^T K/16) -> V P^T -> proj -> +res
// b=8, c=256, n=64*64=4096, groups=32 (8 ch/group)
// All GEMMs via v_mfma_f32_16x16x32_bf16, fp32 accumulation.
// Fragment conventions (verified r1-r4, absmax 0.031):
//   A-frag: lane l holds A[mbase + (l&15)][kbase + 8*(l>>4) + e], e=0..7 (16B)
//   B-frag: lane l holds B[kbase + 8*(l>>4) + e][nbase + (l&15)]
//   D-frag: reg r -> row = 4*(l>>4)+r, col = (l&15)   [HW-verified m89]
// Attn r5: P-LAG PIPELINE. One K buffer + dbuf P/alpha. Region1 (after barA):
// PV(jt-1) + V(jt) reg-loads + QK(jt). Region2 (after barB): K-DMA(jt+1) +
// softmax(jt). barA waits only on ops issued >= half an iteration ago.
// ---------------------------------------------------------------------------

#define NB   8
#define NC   256
#define NPIX 4096
#define CPG  8

typedef __attribute__((ext_vector_type(8))) short bf16x8;
typedef __attribute__((ext_vector_type(4))) short s16x4;
typedef __attribute__((ext_vector_type(8))) short s16x8;
typedef __attribute__((ext_vector_type(4))) float f32x4;

__device__ __forceinline__ short f2bf(float f) {
  union { float f; uint32_t u; } v; v.f = f;
  return (short)((v.u + 0x7fffu + ((v.u >> 16) & 1u)) >> 16);
}

__device__ __forceinline__ uint32_t cvtpk_bf(float a, float b) {
  uint32_t r;
  asm("v_cvt_pk_bf16_f32 %0, %1, %2" : "=v"(r) : "v"(a), "v"(b));
  return r;
}

__device__ __forceinline__ f32x4 mfma16(bf16x8 a, bf16x8 b, f32x4 c) {
  return __builtin_amdgcn_mfma_f32_16x16x32_bf16(a, b, c, 0, 0, 0);
}

__device__ __forceinline__ void gload_lds16(const short* g, short* l) {
  __builtin_amdgcn_global_load_lds(
      (const __attribute__((address_space(1))) void*)g,
      (__attribute__((address_space(3))) void*)l, 16, 0, 0);
}

// ---------------------------------------------------------------------------
// K0: fp32 -> bf16 convert for the 4 weight matrices (one launch)
__global__ __launch_bounds__(256) void wconv4(
    const float* __restrict__ w0, const float* __restrict__ w1,
    const float* __restrict__ w2, const float* __restrict__ w3,
    short* __restrict__ o0, short* __restrict__ o1,
    short* __restrict__ o2, short* __restrict__ o3) {
  int m = blockIdx.x >> 6;
  const float* w = (m == 0) ? w0 : (m == 1) ? w1 : (m == 2) ? w2 : w3;
  short* o = (m == 0) ? o0 : (m == 1) ? o1 : (m == 2) ? o2 : o3;
  int i = ((blockIdx.x & 63) * 256 + threadIdx.x) * 4;
  float4 v = *reinterpret_cast<const float4*>(w + i);
  s16x4 p;
  p[0] = f2bf(v.x); p[1] = f2bf(v.y); p[2] = f2bf(v.z); p[3] = f2bf(v.w);
  *reinterpret_cast<s16x4*>(o + i) = p;
}

// ---------------------------------------------------------------------------
// K1: GroupNorm. One block per (b,g). Writes x_dash transposed: xdt[b][pix][c] bf16.
__global__ __launch_bounds__(256) void gnorm(const float* __restrict__ x,
                                             const float* __restrict__ gw,
                                             const float* __restrict__ gb,
                                             short* __restrict__ xdt) {
  int b = blockIdx.x >> 5;
  int g = blockIdx.x & 31;
  const float* xp = x + ((size_t)b * NC + (size_t)g * CPG) * NPIX;
  int t = threadIdx.x;

  float s = 0.f, ss = 0.f;
  const float4* xp4 = reinterpret_cast<const float4*>(xp);
  for (int i = t; i < (CPG * NPIX) / 4; i += 256) {
    float4 v = xp4[i];
    s  += v.x + v.y + v.z + v.w;
    ss += v.x * v.x + v.y * v.y + v.z * v.z + v.w * v.w;
  }
  for (int m = 32; m; m >>= 1) { s += __shfl_xor(s, m); ss += __shfl_xor(ss, m); }
  __shared__ float red[10];
  int wid = t >> 6;
  if ((t & 63) == 0) { red[wid] = s; red[4 + wid] = ss; }
  __syncthreads();
  if (t == 0) {
    float a  = red[0] + red[1] + red[2] + red[3];
    float b2 = red[4] + red[5] + red[6] + red[7];
    float mean = a * (1.f / 32768.f);
    float var  = b2 * (1.f / 32768.f) - mean * mean;
    red[8] = mean;
    red[9] = rsqrtf(var + 1e-5f);
  }
  __syncthreads();
  float mean = red[8], rstd = red[9];

  float wv2[CPG], bv2[CPG];
  for (int cc = 0; cc < CPG; ++cc) {
    float wgt = gw[g * CPG + cc] * rstd;
    wv2[cc] = wgt;
    bv2[cc] = gb[g * CPG + cc] - mean * wgt;
  }
  for (int pix = t; pix < NPIX; pix += 256) {
    s16x8 pk;
    for (int cc = 0; cc < CPG; ++cc)
      pk[cc] = f2bf(fmaf(xp[cc * NPIX + pix], wv2[cc], bv2[cc]));
    *reinterpret_cast<s16x8*>(&xdt[((size_t)b * NPIX + pix) * NC + g * CPG]) = pk;
  }
}

// ---------------------------------------------------------------------------
// K2: QKV GEMM. grid(64 ntiles, 8 b, 3 mat). OUT[o][n] = sum_c W[o][c] xd[c][n] + bias.
// Q,K stored transposed [b][n][o]; V stored [b][o][n]. LDS tile XOR-swizzled (T2).
__global__ __launch_bounds__(256) void qkv_gemm(
    const short* __restrict__ wq_bf, const short* __restrict__ wk_bf,
    const short* __restrict__ wv_bf,
    const float* __restrict__ bq, const float* __restrict__ bk,
    const float* __restrict__ bv,
    const short* __restrict__ xdt,
    short* __restrict__ qt, short* __restrict__ kt, short* __restrict__ vv) {
  int nt = blockIdx.x, b = blockIdx.y, mi = blockIdx.z;
  const short* W; const float* bia;
  if (mi == 0)      { W = wq_bf; bia = bq; }
  else if (mi == 1) { W = wk_bf; bia = bk; }
  else              { W = wv_bf; bia = bv; }

  __shared__ short xtile[64 * 256];
  __shared__ float bias_lds[256];
  int t = threadIdx.x;
  const short* xg = xdt + ((size_t)b * NPIX + nt * 64) * NC;
  for (int it = 0; it < 8; ++it) {
    int id = t + it * 256, row = id >> 5, part = id & 31;
    *reinterpret_cast<uint4*>(&xtile[row * 256 + (part ^ (row & 7)) * 8]) =
        *reinterpret_cast<const uint4*>(&xg[(size_t)row * 256 + part * 8]);
  }
  bias_lds[t] = bia[t];
  __syncthreads();

  int w = t >> 6, lane = t & 63, g = lane >> 4, lr = lane & 15;
  f32x4 acc[4][4];
  f32x4 zz = {0.f, 0.f, 0.f, 0.f};
  for (int i = 0; i < 4; ++i) for (int j = 0; j < 4; ++j) acc[i][j] = zz;

  for (int c0 = 0; c0 < 256; c0 += 32) {
    bf16x8 af[4], bfr[4];
    for (int mf = 0; mf < 4; ++mf)
      af[mf] = *reinterpret_cast<const bf16x8*>(
          &W[(size_t)(w * 64 + mf * 16 + lr) * 256 + c0 + g * 8]);
    for (int nf = 0; nf < 4; ++nf) {
      int row = nf * 16 + lr;
      bfr[nf] = *reinterpret_cast<const bf16x8*>(
          &xtile[row * 256 + (((c0 >> 3) + g) ^ (row & 7)) * 8]);
    }
    for (int mf = 0; mf < 4; ++mf)
      for (int nf = 0; nf < 4; ++nf)
        acc[mf][nf] = mfma16(af[mf], bfr[nf], acc[mf][nf]);
  }

  if (mi < 2) {
    short* outp = (mi == 0) ? qt : kt;
    for (int mf = 0; mf < 4; ++mf)
      for (int nf = 0; nf < 4; ++nf) {
        int ob = w * 64 + mf * 16 + g * 4;
        int n  = nt * 64 + nf * 16 + lr;
        s16x4 pk;
        for (int r = 0; r < 4; ++r)
          pk[r] = f2bf(acc[mf][nf][r] + bias_lds[ob + r]);
        *reinterpret_cast<s16x4*>(&outp[((size_t)b * NPIX + n) * NC + ob]) = pk;
      }
  } else {
    for (int mf = 0; mf < 4; ++mf)
      for (int nf = 0; nf < 4; ++nf) {
        int ob = w * 64 + mf * 16 + g * 4;
        int n  = nt * 64 + nf * 16 + lr;
        for (int r = 0; r < 4; ++r)
          vv[((size_t)b * NC + ob + r) * NPIX + n] =
              f2bf(acc[mf][nf][r] + bias_lds[ob + r]);
      }
  }
}

// ---------------------------------------------------------------------------
// K3: flash attention, P-lag pipeline. grid(8 b, 64 itiles).
// Wave w: softmax q-rows [16w,16w+16) (lane owns q=16w+lr); O c-rows [64w,64w+64).
// P stored [2][64 q][64 j] bf16 with 16B-chunk XOR swizzle: chunk' = chunk ^ (q&7).
__global__ __launch_bounds__(256, 2) void attn(
    const short* __restrict__ qt, const short* __restrict__ kt,
    const short* __restrict__ vv, short* __restrict__ ot) {
  int b = blockIdx.x, itile = blockIdx.y;
  __shared__ short ktile[64 * 256];
  __shared__ short Pb[2][64 * 64];
  __shared__ float alpha_lds[2][64];

  int t = threadIdx.x, w = t >> 6, lane = t & 63, g = lane >> 4, lr = lane & 15;
  int i0 = itile * 64;

  const short* ktg = kt + (size_t)b * NPIX * NC;

  // prologue: K-DMA(0)
  for (int it = 0; it < 8; ++it) {
    int id = it * 256 + t, row = id >> 5, ch = id & 31;
    gload_lds16(ktg + row * 256 + (ch ^ (row & 7)) * 8, &ktile[id * 8]);
  }
  const short* kgp = ktg + 16384;  // tile jt+1 base

  bf16x8 qf[8];
  {
    const short* qrow = qt + ((size_t)b * NPIX + i0 + w * 16 + lr) * NC;
    for (int ks = 0; ks < 8; ++ks)
      qf[ks] = *reinterpret_cast<const bf16x8*>(&qrow[ks * 32 + g * 8]);
  }

  // V base pointer for this lane (advances 64 shorts per jt)
  const short* vp = vv + (size_t)b * NC * NPIX + (size_t)(w * 64 + lr) * NPIX + g * 8;

  // P LDS offsets (shorts), jt-invariant
  int q_loc = w * 16 + lr;
  int pw[4];
  for (int mf = 0; mf < 4; ++mf)
    pw[mf] = q_loc * 64 + (((mf * 2 + (g >> 1)) ^ (q_loc & 7)) * 8) + (g & 1) * 4;
  int pr[4][2];
  for (int nf = 0; nf < 4; ++nf)
    for (int ks2 = 0; ks2 < 2; ++ks2) {
      int qq = nf * 16 + lr;
      pr[nf][ks2] = qq * 64 + (((ks2 * 4 + g) ^ (qq & 7)) * 8);
    }

  f32x4 zz = {0.f, 0.f, 0.f, 0.f};
  f32x4 oacc[4][4];
  for (int i = 0; i < 4; ++i) for (int j = 0; j < 4; ++j) oacc[i][j] = zz;
  bf16x8 va[2][4];
  float m_ = -1e30f, l_ = 0.f;

  const float sc = 0.0625f, L2E = 1.44269504f;
  const float SCL = sc * L2E;

  for (int jt = 0; jt < 64; ++jt) {
    int cur = jt & 1, prv = cur ^ 1;

    // barA: K(jt) DMA done; P/alpha(jt-1) visible; va(jt-1) loaded.
    // Everything outstanding was issued >= half an iteration ago.
    asm volatile("s_waitcnt vmcnt(0) lgkmcnt(0)" ::: "memory");
    __builtin_amdgcn_s_barrier();
    asm volatile("" ::: "memory");

    // ---- region 1: PV(jt-1), V(jt) issue, QK(jt) ----
    if (jt > 0) {
      float av[4];
      for (int nf = 0; nf < 4; ++nf) av[nf] = alpha_lds[prv][nf * 16 + lr];
      if (__any((av[0] != 1.f) | (av[1] != 1.f) | (av[2] != 1.f) | (av[3] != 1.f))) {
        for (int mf = 0; mf < 4; ++mf)
          for (int nf = 0; nf < 4; ++nf) oacc[mf][nf] *= av[nf];
      }
      __builtin_amdgcn_s_setprio(1);
      for (int ks2 = 0; ks2 < 2; ++ks2) {
        bf16x8 pb[4];
        for (int nf = 0; nf < 4; ++nf)
          pb[nf] = *reinterpret_cast<const bf16x8*>(&Pb[prv][pr[nf][ks2]]);
        for (int mf = 0; mf < 4; ++mf)
          for (int nf = 0; nf < 4; ++nf)
            oacc[mf][nf] = mfma16(va[ks2][mf], pb[nf], oacc[mf][nf]);
      }
      __builtin_amdgcn_s_setprio(0);
    }

    // V(jt) into regs (consumed next iteration; full iter of latency slack)
    for (int ks2 = 0; ks2 < 2; ++ks2)
      for (int mf = 0; mf < 4; ++mf)
        va[ks2][mf] = *reinterpret_cast<const bf16x8*>(
            vp + (size_t)mf * (16 * NPIX) + ks2 * 32);
    vp += 64;

    // QK(jt): S^T = K Q^T
    f32x4 s[4];
    for (int mf = 0; mf < 4; ++mf) s[mf] = zz;
    __builtin_amdgcn_s_setprio(1);
    for (int ks = 0; ks < 8; ++ks) {
      bf16x8 kf[4];
      for (int mf = 0; mf < 4; ++mf) {
        int row = mf * 16 + lr;
        kf[mf] = *reinterpret_cast<const bf16x8*>(
            &ktile[row * 256 + (((ks * 4) + g) ^ (row & 7)) * 8]);
      }
      for (int mf = 0; mf < 4; ++mf) s[mf] = mfma16(kf[mf], qf[ks], s[mf]);
    }
    __builtin_amdgcn_s_setprio(0);

    // barB: all waves done reading ktile(jt) (and Pb[prv])
    asm volatile("s_waitcnt lgkmcnt(0)" ::: "memory");
    __builtin_amdgcn_s_barrier();
    asm volatile("" ::: "memory");

    // ---- region 2: K-DMA(jt+1), softmax(jt) ----
    for (int it = 0; it < 8; ++it) {
      int id = it * 256 + t, row = id >> 5, ch = id & 31;
      gload_lds16(kgp + row * 256 + (ch ^ (row & 7)) * 8, &ktile[id * 8]);
    }
    kgp += 16384;  // jt=63 prefetches harmless junk (in-bounds of ws)

    float mx = s[0][0];
    for (int mf = 0; mf < 4; ++mf)
      for (int r = 0; r < 4; ++r) mx = fmaxf(mx, s[mf][r]);
    mx = fmaxf(mx, __shfl_xor(mx, 16));
    mx = fmaxf(mx, __shfl_xor(mx, 32));
    float pm = mx * sc;
    float mn = (pm - m_ <= 8.f) ? m_ : pm;   // defer-max (T13)
    float alpha = exp2f((m_ - mn) * L2E);
    float mnl = mn * L2E;
    float ps = 0.f;
    for (int mf = 0; mf < 4; ++mf) {
      float p0 = exp2f(fmaf(s[mf][0], SCL, -mnl));
      float p1 = exp2f(fmaf(s[mf][1], SCL, -mnl));
      float p2 = exp2f(fmaf(s[mf][2], SCL, -mnl));
      float p3 = exp2f(fmaf(s[mf][3], SCL, -mnl));
      ps += p0 + p1 + p2 + p3;
      uint2 pk;
      pk.x = cvtpk_bf(p0, p1);
      pk.y = cvtpk_bf(p2, p3);
      *reinterpret_cast<uint2*>(&Pb[cur][pw[mf]]) = pk;
    }
    ps += __shfl_xor(ps, 16);
    ps += __shfl_xor(ps, 32);
    l_ = l_ * alpha + ps;
    m_ = mn;
    if (lane < 16) alpha_lds[cur][w * 16 + lane] = alpha;
  }

  // epilogue: PV(63) with prv = 1
  asm volatile("s_waitcnt vmcnt(0) lgkmcnt(0)" ::: "memory");
  __builtin_amdgcn_s_barrier();
  asm volatile("" ::: "memory");
  {
    float av[4];
    for (int nf = 0; nf < 4; ++nf) av[nf] = alpha_lds[1][nf * 16 + lr];
    if (__any((av[0] != 1.f) | (av[1] != 1.f) | (av[2] != 1.f) | (av[3] != 1.f))) {
      for (int mf = 0; mf < 4; ++mf)
        for (int nf = 0; nf < 4; ++nf) oacc[mf][nf] *= av[nf];
    }
    for (int ks2 = 0; ks2 < 2; ++ks2) {
      bf16x8 pb[4];
      for (int nf = 0; nf < 4; ++nf)
        pb[nf] = *reinterpret_cast<const bf16x8*>(&Pb[1][pr[nf][ks2]]);
      for (int mf = 0; mf < 4; ++mf)
        for (int nf = 0; nf < 4; ++nf)
          oacc[mf][nf] = mfma16(va[ks2][mf], pb[nf], oacc[mf][nf]);
    }
  }

  // lsum exchange (reuse alpha_lds[0])
  if (lane < 16) alpha_lds[0][w * 16 + lane] = l_;
  __syncthreads();

  for (int nf = 0; nf < 4; ++nf) {
    float inv = 1.f / alpha_lds[0][nf * 16 + lr];
    int i = i0 + nf * 16 + lr;
    for (int mf = 0; mf < 4; ++mf) {
      int cb = w * 64 + mf * 16 + g * 4;
      s16x4 pk;
      for (int r = 0; r < 4; ++r) pk[r] = f2bf(oacc[mf][nf][r] * inv);
      *reinterpret_cast<s16x4*>(&ot[((size_t)b * NPIX + i) * NC + cb]) = pk;
    }
  }
}

// ---------------------------------------------------------------------------
// K4: proj + residual. out[b][o][n] = x + gamma*(sum_c wp[o][c]*O[c][n] + bp[o])
__global__ __launch_bounds__(256) void proj_res(
    const short* __restrict__ wp_bf, const float* __restrict__ bp,
    const short* __restrict__ ot, const float* __restrict__ x,
    const float* __restrict__ gamma, float* __restrict__ out) {
  int nt = blockIdx.x, b = blockIdx.y;
  __shared__ short otile[64 * 256];
  __shared__ float bias_lds[256];
  int t = threadIdx.x;
  const short* og = ot + ((size_t)b * NPIX + nt * 64) * NC;
  for (int itx = 0; itx < 8; ++itx) {
    int id = t + itx * 256, row = id >> 5, part = id & 31;
    *reinterpret_cast<uint4*>(&otile[row * 256 + (part ^ (row & 7)) * 8]) =
        *reinterpret_cast<const uint4*>(&og[(size_t)row * 256 + part * 8]);
  }
  bias_lds[t] = bp[t];
  __syncthreads();

  int w = t >> 6, lane = t & 63, g = lane >> 4, lr = lane & 15;
  f32x4 acc[4][4];
  f32x4 zz = {0.f, 0.f, 0.f, 0.f};
  for (int i = 0; i < 4; ++i) for (int j = 0; j < 4; ++j) acc[i][j] = zz;

  for (int c0 = 0; c0 < 256; c0 += 32) {
    bf16x8 af[4], bfr[4];
    for (int mf = 0; mf < 4; ++mf)
      af[mf] = *reinterpret_cast<const bf16x8*>(
          &wp_bf[(size_t)(w * 64 + mf * 16 + lr) * 256 + c0 + g * 8]);
    for (int nf = 0; nf < 4; ++nf) {
      int row = nf * 16 + lr;
      bfr[nf] = *reinterpret_cast<const bf16x8*>(
          &otile[row * 256 + (((c0 >> 3) + g) ^ (row & 7)) * 8]);
    }
    for (int mf = 0; mf < 4; ++mf)
      for (int nf = 0; nf < 4; ++nf)
        acc[mf][nf] = mfma16(af[mf], bfr[nf], acc[mf][nf]);
  }

  float gm = gamma[0];
  for (int mf = 0; mf < 4; ++mf)
    for (int nf = 0; nf < 4; ++nf) {
      int ob = w * 64 + mf * 16 + g * 4;
      int n  = nt * 64 + nf * 16 + lr;
      for (int r = 0; r < 4; ++r) {
        size_t idx = ((size_t)b * NC + ob + r) * NPIX + n;
        out[idx] = x[idx] + gm * (acc[mf][nf][r] + bias_lds[ob + r]);
      }
    }
}

// ---------------------------------------------------------------------------
extern "C" void kernel_launch(void* const* d_in, const int* in_sizes, int n_in,
                              void* d_out, int out_size, void* d_ws, size_t ws_size,
                              hipStream_t stream) {
  (void)in_sizes; (void)n_in; (void)out_size; (void)ws_size;
  const float* x     = (const float*)d_in[0];
  const float* gn_w  = (const float*)d_in[1];
  const float* gn_b  = (const float*)d_in[2];
  const float* wq    = (const float*)d_in[3];
  const float* bq    = (const float*)d_in[4];
  const float* wk    = (const float*)d_in[5];
  const float* bk    = (const float*)d_in[6];
  const float* wv    = (const float*)d_in[7];
  const float* bv    = (const float*)d_in[8];
  const float* wp    = (const float*)d_in[9];
  const float* bp    = (const float*)d_in[10];
  const float* gamma = (const float*)d_in[11];
  float* out = (float*)d_out;

  char* ws = (char*)d_ws;
  const size_t WSZ = 131072;                      // 256*256*2B
  const size_t TSZ = (size_t)NB * NPIX * NC * 2;  // 16.78MB
  short* wq_bf = (short*)(ws);
  short* wk_bf = (short*)(ws + WSZ);
  short* wv_bf = (short*)(ws + 2 * WSZ);
  short* wp_bf = (short*)(ws + 3 * WSZ);
  short* xdt   = (short*)(ws + 4 * WSZ);          // reused as Ot after K2
  short* qt    = (short*)(ws + 4 * WSZ + TSZ);
  short* kt    = (short*)(ws + 4 * WSZ + 2 * TSZ);
  short* vv    = (short*)(ws + 4 * WSZ + 3 * TSZ);
  short* ot    = xdt;

  wconv4<<<256, 256, 0, stream>>>(wq, wk, wv, wp, wq_bf, wk_bf, wv_bf, wp_bf);

  gnorm<<<256, 256, 0, stream>>>(x, gn_w, gn_b, xdt);

  qkv_gemm<<<dim3(64, 8, 3), 256, 0, stream>>>(wq_bf, wk_bf, wv_bf, bq, bk, bv,
                                               xdt, qt, kt, vv);

  attn<<<dim3(8, 64), 256, 0, stream>>>(qt, kt, vv, ot);

  proj_res<<<dim3(64, 8), 256, 0, stream>>>(wp_bf, bp, ot, x, gamma, out);
}